// Round 2
// baseline (6203.036 us; speedup 1.0000x reference)
//
#include <hip/hip_runtime.h>
#include <stdint.h>

#define CDIV(a,b) (((a)+(b)-1)/(b))

typedef __attribute__((ext_vector_type(4))) float f32x4;
typedef __attribute__((ext_vector_type(8))) short s16x8;
typedef __attribute__((ext_vector_type(8))) unsigned short u16x8;
typedef __attribute__((ext_vector_type(4))) unsigned short u16x4;

__device__ __forceinline__ float bf2f(unsigned short u) {
  union { unsigned int i; float f; } c; c.i = ((unsigned int)u) << 16; return c.f;
}
__device__ __forceinline__ unsigned short f2bf(float f) {
  union { float f; unsigned int i; } c; c.f = f;
  unsigned int u = c.i;
  u += 0x7fffu + ((u >> 16) & 1u);
  return (unsigned short)(u >> 16);
}

// ===== GEMM: C[M,N] = A(bf16)[M,K] * B(bf16)[N,K]^T =====
// EPI: 0 = f32 store, 1 = bf16 store, 3 = bf16 * zp[r] (offs-batched over graphs),
//      5 = f32 += relu(acc + aux[col])
template<int BM, int BN, int WM, int WN, int EPI>
__global__ __launch_bounds__(256) void gemm_bt(
    const unsigned short* __restrict__ A, const unsigned short* __restrict__ B,
    void* __restrict__ Cout, const float* __restrict__ aux,
    const unsigned int* __restrict__ offs,
    int K, int lda, int ldb, int ldc,
    long zsA, long zsB, long zsC, int Mstore)
{
  constexpr int MT = BM / (WM * 16);
  constexpr int NT = BN / (WN * 16);
  constexpr int LDT = 40;  // padded LDS row stride (ushorts)
  __shared__ unsigned short As[BM * LDT];
  __shared__ unsigned short Bs[BN * LDT];
  const int tid = threadIdx.x, wid = tid >> 6, lane = tid & 63;
  const int wr = wid / WN, wc = wid % WN;
  long m0 = (long)blockIdx.y * BM;
  const int n0 = blockIdx.x * BN;
  const int z = blockIdx.z;
  A += (long)z * zsA; B += (long)z * zsB;
  long coff = (long)z * zsC;
  const float* zp = aux;
  int mstore = Mstore;
  if constexpr (EPI == 3) {
    unsigned int off = offs[z];
    int nb = (int)(offs[z + 1] - off);
    if (m0 >= nb) return;
    A += (long)off * lda;
    coff += (long)off * ldc;
    zp = aux + off;
    mstore = nb;
  }
  f32x4 acc[MT][NT] = {};
  for (int k0 = 0; k0 < K; k0 += 32) {
    #pragma unroll
    for (int c = tid; c < BM * 4; c += 256) {
      int row = c >> 2, c8 = (c & 3) * 8;
      *(u16x8*)(&As[row * LDT + c8]) = *(const u16x8*)(A + (m0 + row) * lda + k0 + c8);
    }
    #pragma unroll
    for (int c = tid; c < BN * 4; c += 256) {
      int row = c >> 2, c8 = (c & 3) * 8;
      *(u16x8*)(&Bs[row * LDT + c8]) = *(const u16x8*)(B + (long)(n0 + row) * ldb + k0 + c8);
    }
    __syncthreads();
    s16x8 af[MT], bfv[NT];
    #pragma unroll
    for (int mt = 0; mt < MT; mt++)
      af[mt] = *(const s16x8*)(&As[(wr * MT * 16 + mt * 16 + (lane & 15)) * LDT + ((lane >> 4) * 8)]);
    #pragma unroll
    for (int nt = 0; nt < NT; nt++)
      bfv[nt] = *(const s16x8*)(&Bs[(wc * NT * 16 + nt * 16 + (lane & 15)) * LDT + ((lane >> 4) * 8)]);
    #pragma unroll
    for (int mt = 0; mt < MT; mt++)
      #pragma unroll
      for (int nt = 0; nt < NT; nt++)
        acc[mt][nt] = __builtin_amdgcn_mfma_f32_16x16x32_bf16(af[mt], bfv[nt], acc[mt][nt], 0, 0, 0);
    __syncthreads();
  }
  #pragma unroll
  for (int mt = 0; mt < MT; mt++) {
    const int rl0 = wr * (MT * 16) + mt * 16 + ((lane >> 4) << 2);
    #pragma unroll
    for (int nt = 0; nt < NT; nt++) {
      const int col = n0 + wc * (NT * 16) + nt * 16 + (lane & 15);
      #pragma unroll
      for (int i = 0; i < 4; i++) {
        long r = m0 + rl0 + i;
        if (r < mstore) {
          float v = acc[mt][nt][i];
          long ci = coff + r * ldc + col;
          if constexpr (EPI == 0) ((float*)Cout)[ci] = v;
          else if constexpr (EPI == 1) ((unsigned short*)Cout)[ci] = f2bf(v);
          else if constexpr (EPI == 3) ((unsigned short*)Cout)[ci] = f2bf(v * zp[r]);
          else if constexpr (EPI == 5) {
            float o = v + aux[col];
            o = o > 0.f ? o : 0.f;
            ((float*)Cout)[ci] += o;
          }
        }
      }
    }
  }
}

// ===== small kernels =====

__global__ void k_fill(float* __restrict__ out, long n, float v) {
  long i = (long)blockIdx.x * 256 + threadIdx.x;
  if (i < n) out[i] = v;
}

__global__ void k_convert_x(const float* __restrict__ x, unsigned short* __restrict__ xb,
                            long ntotal, long nreal) {
  long i = ((long)blockIdx.x * 256 + threadIdx.x) * 4;
  if (i >= ntotal) return;
  u16x4 o;
  if (i < nreal) {
    f32x4 v = *(const f32x4*)(x + i);
    o[0] = f2bf(v[0]); o[1] = f2bf(v[1]); o[2] = f2bf(v[2]); o[3] = f2bf(v[3]);
  } else { o[0] = 0; o[1] = 0; o[2] = 0; o[3] = 0; }
  *(u16x4*)(xb + i) = o;
}

__global__ void k_transpose_w(const float* __restrict__ w, unsigned short* __restrict__ out) {
  int idx = blockIdx.x * 256 + threadIdx.x;
  if (idx >= 512 * 512) return;
  int n = idx >> 9, k = idx & 511;
  out[idx] = f2bf(w[k * 512 + n]);
}

__global__ void k_scale_copy_bf(const float* __restrict__ in, unsigned short* __restrict__ out,
                                int n, float scl) {
  int i = blockIdx.x * 256 + threadIdx.x;
  if (i < n) out[i] = f2bf(in[i] * scl);
}

__global__ void k_bn_stats(const float* __restrict__ x, float* __restrict__ s1,
                           float* __restrict__ s2, int N, int rpb) {
  int t = threadIdx.x;
  int r0 = blockIdx.x * rpb;
  int r1 = min(N, r0 + rpb);
  float a1 = 0, a2 = 0, b1 = 0, b2 = 0;
  for (int r = r0; r < r1; r++) {
    float va = x[(long)r * 512 + t];
    float vb = x[(long)r * 512 + t + 256];
    a1 += va; a2 += va * va; b1 += vb; b2 += vb * vb;
  }
  atomicAdd(&s1[t], a1); atomicAdd(&s2[t], a2);
  atomicAdd(&s1[t + 256], b1); atomicAdd(&s2[t + 256], b2);
}

__global__ void k_bn_final(const float* __restrict__ s1, const float* __restrict__ s2,
                           const float* __restrict__ g, const float* __restrict__ b,
                           float* __restrict__ a, float* __restrict__ c, float invN) {
  int t = threadIdx.x;
  float mu = s1[t] * invN;
  float var = s2[t] * invN - mu * mu;
  float inv = rsqrtf(var + 1e-5f);
  float av = g[t] * inv;
  a[t] = av;
  c[t] = b[t] - mu * av;
}

__global__ void k_deg_counts(const int* __restrict__ ed, unsigned int* __restrict__ deg,
                             const int* __restrict__ batch, unsigned int* __restrict__ counts,
                             long E, int N) {
  long i = (long)blockIdx.x * 256 + threadIdx.x;
  if (i < E) atomicAdd(&deg[ed[i]], 1u);
  if (i < N) atomicAdd(&counts[batch[i]], 1u);
}

__global__ void k_scan(const unsigned int* __restrict__ counts, unsigned int* __restrict__ offs) {
  if (threadIdx.x == 0) {
    unsigned int s = 0;
    for (int b = 0; b < 32; b++) { offs[b] = s; s += counts[b]; }
    offs[32] = s;
  }
}

__global__ void k_scatter(const int* __restrict__ es, const int* __restrict__ ed,
                          const float* __restrict__ x, float* __restrict__ agg, long E) {
  long idx = (long)blockIdx.x * 256 + threadIdx.x;
  if (idx >= E * 128) return;
  long e = idx >> 7;
  int q = (int)(idx & 127) << 2;
  int s = es[e], d = ed[e];
  f32x4 v = *(const f32x4*)(x + (long)s * 512 + q);
  float* p = agg + (long)d * 512 + q;
  atomicAdd(p + 0, v[0]); atomicAdd(p + 1, v[1]);
  atomicAdd(p + 2, v[2]); atomicAdd(p + 3, v[3]);
}

__global__ void k_conv_in(const float* __restrict__ agg, const unsigned int* __restrict__ deg,
                          const float* __restrict__ a1, const float* __restrict__ c1,
                          unsigned short* __restrict__ out, long npad512, long N) {
  long i4 = ((long)blockIdx.x * 256 + threadIdx.x) * 4;
  if (i4 >= npad512) return;
  long r = i4 >> 9;
  int c = (int)(i4 & 511);
  u16x4 o;
  o[0] = 0; o[1] = 0; o[2] = 0; o[3] = 0;
  if (r < N) {
    unsigned int d = deg[r];
    if (d) {
      float inv = 1.f / (float)d;
      f32x4 v = *(const f32x4*)(agg + i4);
      o[0] = f2bf(v[0] * inv * a1[c + 0] + c1[c + 0]);
      o[1] = f2bf(v[1] * inv * a1[c + 1] + c1[c + 1]);
      o[2] = f2bf(v[2] * inv * a1[c + 2] + c1[c + 2]);
      o[3] = f2bf(v[3] * inv * a1[c + 3] + c1[c + 3]);
    }
  }
  *(u16x4*)(out + i4) = o;
}

// diag[h*Npad + n] = 0.0625 * sum_d t[n,d]^2  (t = head z of kvqh, zoff selects q/k block)
__global__ void k_diag_all(const unsigned short* __restrict__ kvqh, float* __restrict__ diag,
                           long Npad, int N, int zoff) {
  int n = blockIdx.x * 4 + (threadIdx.x >> 6);
  int h = blockIdx.y;
  int lane = threadIdx.x & 63;
  if (n >= N) return;
  float v = bf2f(kvqh[((long)(zoff + h) * Npad + n) * 64 + lane]);
  float sq = v * v;
  for (int s = 1; s < 64; s <<= 1) sq += __shfl_xor(sq, s);
  if (lane == 0) diag[(long)h * Npad + n] = 0.0625f * sq;
}

__global__ void k_kmax(const float* __restrict__ u, const int* __restrict__ batch,
                       unsigned int* __restrict__ kmax, int h, int N) {
  int n = blockIdx.x * 4 + (threadIdx.x >> 6);
  int lane = threadIdx.x & 63;
  if (n >= N) return;
  f32x4 v = *(const f32x4*)(u + (long)n * 256 + lane * 4);
  float m = fmaxf(fmaxf(v[0], v[1]), fmaxf(v[2], v[3]));
  for (int s = 1; s < 64; s <<= 1) m = fmaxf(m, __shfl_xor(m, s));
  m = fmaxf(m, 0.f);  // padded rows contribute u=0 in the reference
  if (lane == 0) atomicMax(&kmax[batch[n] * 8 + h], __float_as_uint(m));
}

__global__ void k_kf(const float* __restrict__ u, const float* __restrict__ dptr,
                     const unsigned int* __restrict__ kmax, const int* __restrict__ batch,
                     unsigned short* __restrict__ kf, int h, int N) {
  int n = blockIdx.x * 4 + (threadIdx.x >> 6);
  int lane = threadIdx.x & 63;
  if (n >= N) return;
  float diag = dptr[n];
  float km = __uint_as_float(kmax[batch[n] * 8 + h]);
  f32x4 uv = *(const f32x4*)(u + (long)n * 256 + lane * 4);
  u16x4 o;
  #pragma unroll
  for (int j = 0; j < 4; j++) o[j] = f2bf(__expf(uv[j] - diag - km) * 0.0625f + 1e-6f);
  *(u16x4*)(kf + (long)n * 256 + lane * 4) = o;
}

__global__ void k_qf(const float* __restrict__ u, const float* __restrict__ dptr,
                     const float* __restrict__ kfsum, const int* __restrict__ batch,
                     unsigned short* __restrict__ qf, float* __restrict__ z, int h, int N) {
  int n = blockIdx.x * 4 + (threadIdx.x >> 6);
  int lane = threadIdx.x & 63;
  if (n >= N) return;
  float diag = dptr[n];
  f32x4 uv = *(const f32x4*)(u + (long)n * 256 + lane * 4);
  float m = fmaxf(fmaxf(uv[0], uv[1]), fmaxf(uv[2], uv[3]));
  for (int s = 1; s < 64; s <<= 1) m = fmaxf(m, __shfl_xor(m, s));
  f32x4 e;
  #pragma unroll
  for (int j = 0; j < 4; j++) e[j] = __expf(uv[j] - diag - m) * 0.0625f + 1e-6f;
  u16x4 o;
  #pragma unroll
  for (int j = 0; j < 4; j++) o[j] = f2bf(e[j]);
  *(u16x4*)(qf + (long)n * 256 + lane * 4) = o;
  const float* ks = kfsum + ((long)batch[n] * 8 + h) * 256;
  f32x4 k4 = *(const f32x4*)(ks + lane * 4);
  float dot = e[0] * k4[0] + e[1] * k4[1] + e[2] * k4[2] + e[3] * k4[3];
  for (int s = 1; s < 64; s <<= 1) dot += __shfl_xor(dot, s);
  if (lane == 0) z[n] = 1.f / (dot + 1e-6f);
}

// kvT[b][h][d][m] += sum_i kf[i][m]*v[i][d]; kfsum[b][h][m] += sum_i kf[i][m]
__global__ __launch_bounds__(256) void k_kv(const unsigned short* __restrict__ kf,
                                            const unsigned short* __restrict__ vh,
                                            const unsigned int* __restrict__ offs,
                                            float* __restrict__ kvT, float* __restrict__ kfsum, int h) {
  int b = blockIdx.y;
  unsigned int off = offs[b];
  int nb = (int)(offs[b + 1] - off);
  int start = blockIdx.x * 256;
  if (start >= nb) return;
  int cnt = min(256, nb - start);
  __shared__ float kfs[16][256];
  __shared__ float vs[16][64];
  int tid = threadIdx.x;
  int mg = tid & 63, dg = tid >> 6;  // m0 = mg*4, d0 = dg*16
  f32x4 acc[4][4] = {};
  f32x4 sacc = {};
  for (int g0 = 0; g0 < cnt; g0 += 16) {
    int nv = min(16, cnt - g0);
    for (int c = tid; c < 512; c += 256) {
      int r = c >> 5, c8 = (c & 31) * 8;
      if (r < nv) {
        u16x8 v = *(const u16x8*)(kf + (long)(off + start + g0 + r) * 256 + c8);
        #pragma unroll
        for (int j = 0; j < 8; j++) kfs[r][c8 + j] = bf2f(v[j]);
      }
    }
    {
      int c = tid;
      int r = c >> 4, c4 = (c & 15) * 4;
      if (r < nv) {
        u16x4 v = *(const u16x4*)(vh + (long)(off + start + g0 + r) * 64 + c4);
        #pragma unroll
        for (int j = 0; j < 4; j++) vs[r][c4 + j] = bf2f(v[j]);
      }
    }
    __syncthreads();
    for (int r = 0; r < nv; r++) {
      f32x4 kfv = *(const f32x4*)(&kfs[r][mg * 4]);
      #pragma unroll
      for (int jq = 0; jq < 4; jq++) {
        f32x4 vv = *(const f32x4*)(&vs[r][dg * 16 + jq * 4]);
        #pragma unroll
        for (int mi = 0; mi < 4; mi++) acc[mi][jq] += kfv[mi] * vv;
      }
      if (dg == 0) sacc += kfv;
    }
    __syncthreads();
  }
  long base = ((long)b * 8 + h) * 16384;
  #pragma unroll
  for (int jq = 0; jq < 4; jq++)
    #pragma unroll
    for (int dj = 0; dj < 4; dj++) {
      int d = dg * 16 + jq * 4 + dj;
      #pragma unroll
      for (int mi = 0; mi < 4; mi++)
        atomicAdd(&kvT[base + (long)d * 256 + mg * 4 + mi], acc[mi][jq][dj]);
    }
  if (dg == 0) {
    long sb = ((long)b * 8 + h) * 256 + mg * 4;
    #pragma unroll
    for (int mi = 0; mi < 4; mi++) atomicAdd(&kfsum[sb + mi], sacc[mi]);
  }
}

__global__ void k_f32_to_bf16_4(const float* __restrict__ in, unsigned short* __restrict__ out, long n) {
  long i = ((long)blockIdx.x * 256 + threadIdx.x) * 4;
  if (i >= n) return;
  f32x4 v = *(const f32x4*)(in + i);
  u16x4 o;
  o[0] = f2bf(v[0]); o[1] = f2bf(v[1]); o[2] = f2bf(v[2]); o[3] = f2bf(v[3]);
  *(u16x4*)(out + i) = o;
}

// out += x (residual), accumulate BN2 stats
__global__ void k_sum_x_stats(const float* __restrict__ x, float* __restrict__ y,
                              float* __restrict__ s1, float* __restrict__ s2, int N, int rpb) {
  int t = threadIdx.x;
  int r0 = blockIdx.x * rpb;
  int r1 = min(N, r0 + rpb);
  float a1 = 0, a2 = 0, b1 = 0, b2 = 0;
  for (int r = r0; r < r1; r++) {
    long ia = (long)r * 512 + t;
    long ib = ia + 256;
    float va = x[ia] + y[ia];
    float vb = x[ib] + y[ib];
    y[ia] = va; y[ib] = vb;
    a1 += va; a2 += va * va; b1 += vb; b2 += vb * vb;
  }
  atomicAdd(&s1[t], a1); atomicAdd(&s2[t], a2);
  atomicAdd(&s1[t + 256], b1); atomicAdd(&s2[t + 256], b2);
}

__global__ void k_bn_apply(float* __restrict__ y, const float* __restrict__ a,
                           const float* __restrict__ c, long total) {
  long i4 = ((long)blockIdx.x * 256 + threadIdx.x) * 4;
  if (i4 >= total) return;
  int col = (int)(i4 & 511);
  f32x4 v = *(const f32x4*)(y + i4);
  #pragma unroll
  for (int j = 0; j < 4; j++) v[j] = v[j] * a[col + j] + c[col + j];
  *(f32x4*)(y + i4) = v;
}

// ===== host =====

extern "C" void kernel_launch(void* const* d_in, const int* in_sizes, int n_in,
                              void* d_out, int out_size, void* d_ws, size_t ws_size,
                              hipStream_t stream) {
  (void)n_in; (void)out_size;
  const float* x = (const float*)d_in[0];
  const int* batch = (const int*)d_in[1];
  const int* eidx = (const int*)d_in[2];
  const float* n1g = (const float*)d_in[3];
  const float* n1b = (const float*)d_in[4];
  const float* n2g = (const float*)d_in[5];
  const float* n2b = (const float*)d_in[6];
  const float* wconv = (const float*)d_in[7];
  const float* bconv = (const float*)d_in[8];
  const float* wq = (const float*)d_in[9];
  const float* wk = (const float*)d_in[10];
  const float* wv = (const float*)d_in[11];
  const float* wo = (const float*)d_in[12];
  const float* proj = (const float*)d_in[13];

  const int N = in_sizes[1];
  const long E = in_sizes[2] / 2;
  const long Npad = CDIV(N, 128) * 128;
  const int Mb = (int)(Npad / 128);
  const int* es = eidx;
  const int* ed = eidx + E;
  float* out = (float*)d_out;

  char* p = (char*)d_ws;
  auto alloc = [&](size_t bytes) -> char* {
    char* r = p;
    p += (bytes + 255) & ~(size_t)255;
    return r;
  };
  // Region A: ubuf | kvqh | kf   — later overlaid by agg (f32 N*512) in conv phase
  float*          ubuf = (float*)alloc((size_t)Npad * 256 * 4);          // 49.8 MB
  unsigned short* kvqh = (unsigned short*)alloc((size_t)24 * Npad * 64 * 2); // 37.3 MB (q:0-7,k:8-15,v:16-23)
  unsigned short* kf   = (unsigned short*)alloc((size_t)Npad * 256 * 2); // 24.9 MB (kf then qf)
  // Region B: x_bf -> attn_all -> conv_in
  unsigned short* xbf  = (unsigned short*)alloc((size_t)Npad * 512 * 2); // 49.8 MB
  float*          kvT_f = (float*)alloc((size_t)32 * 8 * 16384 * 4);     // 16.8 MB
  unsigned short* kvT_b = (unsigned short*)alloc((size_t)32 * 8 * 16384 * 2); // 8.4 MB
  float*          diag  = (float*)alloc((size_t)8 * Npad * 4);           // 1.56 MB
  unsigned short* wqkv_t = (unsigned short*)alloc((size_t)24 * 64 * 512 * 2);
  unsigned short* wconv_t = (unsigned short*)alloc((size_t)512 * 512 * 2);
  unsigned short* wo_t   = (unsigned short*)alloc((size_t)512 * 512 * 2);
  unsigned short* proj_s = (unsigned short*)alloc((size_t)256 * 64 * 2);
  float* bn1_acc = (float*)alloc(1024 * 4);
  float* bn1_ac  = (float*)alloc(1024 * 4);
  float* bn2_acc = (float*)alloc(1024 * 4);
  float* bn2_ac  = (float*)alloc(1024 * 4);
  unsigned int* deg    = (unsigned int*)alloc((size_t)N * 4);
  unsigned int* counts = (unsigned int*)alloc(32 * 4);
  unsigned int* offs   = (unsigned int*)alloc(33 * 4);
  unsigned int* kmax   = (unsigned int*)alloc(32 * 8 * 4);
  float* kfsum = (float*)alloc((size_t)32 * 8 * 256 * 4);
  float* zbuf  = (float*)alloc((size_t)N * 4);
  size_t required = (size_t)(p - (char*)d_ws);
  if (required > ws_size) {
    // beacon: encode ws_size (MB) into the output so the failure is diagnosable
    k_fill<<<(int)CDIV((long)N * 512, 256), 256, 0, stream>>>(
        out, (long)N * 512, 1.0e6f + (float)(ws_size >> 20));
    return;
  }
  float* agg = (float*)ubuf;               // overlays region A during conv phase
  unsigned short* attn_all = xbf;          // region B reuse
  unsigned short* conv_in  = xbf;          // region B reuse (after Wo GEMM)

  // sentinel: if the pipeline dies mid-way we'll see ~333333 in the error report
  k_fill<<<(int)CDIV((long)N * 512, 256), 256, 0, stream>>>(out, (long)N * 512, 333333.0f);

  // ---- zero accumulators (every call: ws is not re-poisoned between replays) ----
  hipMemsetAsync(deg, 0, (size_t)N * 4, stream);
  hipMemsetAsync(counts, 0, 32 * 4, stream);
  hipMemsetAsync(kvT_f, 0, (size_t)32 * 8 * 16384 * 4, stream);
  hipMemsetAsync(kfsum, 0, (size_t)32 * 8 * 256 * 4, stream);
  hipMemsetAsync(kmax, 0, 32 * 8 * 4, stream);
  hipMemsetAsync(bn1_acc, 0, 1024 * 4, stream);
  hipMemsetAsync(bn2_acc, 0, 1024 * 4, stream);

  // ---- prep ----
  k_convert_x<<<(int)CDIV(Npad * 512 / 4, 256), 256, 0, stream>>>(x, xbf, Npad * 512, (long)N * 512);
  k_transpose_w<<<CDIV(512 * 512, 256), 256, 0, stream>>>(wq, wqkv_t);                 // q: z 0..7
  k_transpose_w<<<CDIV(512 * 512, 256), 256, 0, stream>>>(wk, wqkv_t + 8 * 64 * 512);  // k: z 8..15
  k_transpose_w<<<CDIV(512 * 512, 256), 256, 0, stream>>>(wv, wqkv_t + 16 * 64 * 512); // v: z 16..23
  k_transpose_w<<<CDIV(512 * 512, 256), 256, 0, stream>>>(wconv, wconv_t);
  k_transpose_w<<<CDIV(512 * 512, 256), 256, 0, stream>>>(wo, wo_t);
  k_scale_copy_bf<<<CDIV(256 * 64, 256), 256, 0, stream>>>(proj, proj_s, 256 * 64, 0.35355339059327373f);

  int rpb = CDIV(N, 1024);
  k_bn_stats<<<1024, 256, 0, stream>>>(x, bn1_acc, bn1_acc + 512, N, rpb);
  k_bn_final<<<1, 512, 0, stream>>>(bn1_acc, bn1_acc + 512, n1g, n1b, bn1_ac, bn1_ac + 512, 1.f / N);
  k_deg_counts<<<(int)CDIV(E, 256), 256, 0, stream>>>(ed, deg, batch, counts, E, N);
  k_scan<<<1, 64, 0, stream>>>(counts, offs);

  // ---- per-head q/k/v projections, one z-batched GEMM (z = 24 head-tensors) ----
  gemm_bt<128, 64, 2, 2, 1><<<dim3(1, Mb, 24), 256, 0, stream>>>(
      xbf, wqkv_t, kvqh, nullptr, nullptr,
      512, 512, 512, 64, 0, (long)64 * 512, (long)Npad * 64, (int)Npad);

  // ---- keys pass ----
  k_diag_all<<<dim3(CDIV(N, 4), 8), 256, 0, stream>>>(kvqh, diag, Npad, N, 8);
  for (int h = 0; h < 8; h++) {
    const unsigned short* kh = kvqh + (long)(8 + h) * Npad * 64;
    const unsigned short* vh = kvqh + (long)(16 + h) * Npad * 64;
    gemm_bt<128, 128, 2, 2, 0><<<dim3(2, Mb), 256, 0, stream>>>(
        kh, proj_s, ubuf, nullptr, nullptr, 64, 64, 64, 256, 0, 0, 0, N);
    k_kmax<<<CDIV(N, 4), 256, 0, stream>>>(ubuf, batch, kmax, h, N);
    k_kf<<<CDIV(N, 4), 256, 0, stream>>>(ubuf, diag + (long)h * Npad, kmax, batch, kf, h, N);
    k_kv<<<dim3(8, 32), 256, 0, stream>>>(kf, vh, offs, kvT_f, kfsum, h);
  }
  k_f32_to_bf16_4<<<CDIV((long)32 * 8 * 16384 / 4, 256), 256, 0, stream>>>(
      kvT_f, kvT_b, (long)32 * 8 * 16384);

  // ---- queries pass ----
  k_diag_all<<<dim3(CDIV(N, 4), 8), 256, 0, stream>>>(kvqh, diag, Npad, N, 0);
  for (int h = 0; h < 8; h++) {
    const unsigned short* qh = kvqh + (long)h * Npad * 64;
    gemm_bt<128, 128, 2, 2, 0><<<dim3(2, Mb), 256, 0, stream>>>(
        qh, proj_s, ubuf, nullptr, nullptr, 64, 64, 64, 256, 0, 0, 0, N);
    k_qf<<<CDIV(N, 4), 256, 0, stream>>>(ubuf, diag + (long)h * Npad, kfsum, batch, kf, zbuf, h, N);
    gemm_bt<256, 64, 4, 1, 3><<<dim3(1, 8, 32), 256, 0, stream>>>(
        kf, kvT_b + (long)h * 16384, attn_all + h * 64, zbuf, offs,
        256, 256, 256, 512, 0, (long)8 * 16384, 0, 1 << 30);
  }

  // ---- output projection (full overwrite of out) ----
  gemm_bt<128, 128, 2, 2, 0><<<dim3(4, Mb), 256, 0, stream>>>(
      attn_all, wo_t, out, nullptr, nullptr, 512, 512, 512, 512, 0, 0, 0, N);

  // ---- GNN conv path (after attention so agg can overlay region A) ----
  hipMemsetAsync(agg, 0, (size_t)N * 512 * 4, stream);
  k_scatter<<<(int)CDIV(E * 128, 256), 256, 0, stream>>>(es, ed, x, agg, E);
  k_conv_in<<<(int)CDIV(Npad * 512 / 4, 256), 256, 0, stream>>>(
      agg, deg, bn1_ac, bn1_ac + 512, conv_in, Npad * 512, N);
  gemm_bt<128, 128, 2, 2, 5><<<dim3(4, Mb), 256, 0, stream>>>(
      conv_in, wconv_t, out, bconv, nullptr, 512, 512, 512, 512, 0, 0, 0, N);

  // ---- residual + BN2 ----
  k_sum_x_stats<<<1024, 256, 0, stream>>>(x, out, bn2_acc, bn2_acc + 512, N, rpb);
  k_bn_final<<<1, 512, 0, stream>>>(bn2_acc, bn2_acc + 512, n2g, n2b, bn2_ac, bn2_ac + 512, 1.f / N);
  k_bn_apply<<<(int)CDIV((long)N * 512 / 4, 256), 256, 0, stream>>>(out, bn2_ac, bn2_ac + 512, (long)N * 512);
}

// Round 3
// 4501.162 us; speedup vs baseline: 1.3781x; 1.3781x over previous
//
#include <hip/hip_runtime.h>
#include <stdint.h>

#define CDIV(a,b) (((a)+(b)-1)/(b))

typedef __attribute__((ext_vector_type(4))) float f32x4;
typedef __attribute__((ext_vector_type(8))) short s16x8;
typedef __attribute__((ext_vector_type(8))) unsigned short u16x8;
typedef __attribute__((ext_vector_type(4))) unsigned short u16x4;

__device__ __forceinline__ float bf2f(unsigned short u) {
  union { unsigned int i; float f; } c; c.i = ((unsigned int)u) << 16; return c.f;
}
__device__ __forceinline__ unsigned short f2bf(float f) {
  union { float f; unsigned int i; } c; c.f = f;
  unsigned int u = c.i;
  u += 0x7fffu + ((u >> 16) & 1u);
  return (unsigned short)(u >> 16);
}

// ===== GEMM: C[M,N] = A(bf16)[M,K] * B(bf16)[N,K]^T =====
// EPI: 0 = f32 store, 1 = bf16 store, 3 = bf16 * zp[r] (offs-batched over graphs),
//      5 = f32 += relu(acc + aux[col]), 6 = f32 store + per-graph row-max atomicMax (kmax in offs)
template<int BM, int BN, int WM, int WN, int EPI>
__global__ __launch_bounds__(256) void gemm_bt(
    const unsigned short* __restrict__ A, const unsigned short* __restrict__ B,
    void* __restrict__ Cout, const float* __restrict__ aux,
    const unsigned int* __restrict__ offs, const int* __restrict__ batchv,
    int K, int lda, int ldb, int ldc,
    long zsA, long zsB, long zsC, int Mstore, int head)
{
  constexpr int MT = BM / (WM * 16);
  constexpr int NT = BN / (WN * 16);
  constexpr int LDT = 40;  // padded LDS row stride (ushorts)
  __shared__ unsigned short As[BM * LDT];
  __shared__ unsigned short Bs[BN * LDT];
  const int tid = threadIdx.x, wid = tid >> 6, lane = tid & 63;
  const int wr = wid / WN, wc = wid % WN;
  long m0 = (long)blockIdx.y * BM;
  const int n0 = blockIdx.x * BN;
  const int z = blockIdx.z;
  A += (long)z * zsA; B += (long)z * zsB;
  long coff = (long)z * zsC;
  const float* zp = aux;
  int mstore = Mstore;
  if constexpr (EPI == 3) {
    unsigned int off = offs[z];
    int nb = (int)(offs[z + 1] - off);
    if (m0 >= nb) return;
    A += (long)off * lda;
    coff += (long)off * ldc;
    zp = aux + off;
    mstore = nb;
  }
  f32x4 acc[MT][NT] = {};
  for (int k0 = 0; k0 < K; k0 += 32) {
    #pragma unroll
    for (int c = tid; c < BM * 4; c += 256) {
      int row = c >> 2, c8 = (c & 3) * 8;
      *(u16x8*)(&As[row * LDT + c8]) = *(const u16x8*)(A + (m0 + row) * lda + k0 + c8);
    }
    #pragma unroll
    for (int c = tid; c < BN * 4; c += 256) {
      int row = c >> 2, c8 = (c & 3) * 8;
      *(u16x8*)(&Bs[row * LDT + c8]) = *(const u16x8*)(B + (long)(n0 + row) * ldb + k0 + c8);
    }
    __syncthreads();
    s16x8 af[MT], bfv[NT];
    #pragma unroll
    for (int mt = 0; mt < MT; mt++)
      af[mt] = *(const s16x8*)(&As[(wr * MT * 16 + mt * 16 + (lane & 15)) * LDT + ((lane >> 4) * 8)]);
    #pragma unroll
    for (int nt = 0; nt < NT; nt++)
      bfv[nt] = *(const s16x8*)(&Bs[(wc * NT * 16 + nt * 16 + (lane & 15)) * LDT + ((lane >> 4) * 8)]);
    #pragma unroll
    for (int mt = 0; mt < MT; mt++)
      #pragma unroll
      for (int nt = 0; nt < NT; nt++)
        acc[mt][nt] = __builtin_amdgcn_mfma_f32_16x16x32_bf16(af[mt], bfv[nt], acc[mt][nt], 0, 0, 0);
    __syncthreads();
  }
  #pragma unroll
  for (int mt = 0; mt < MT; mt++) {
    const int rl0 = wr * (MT * 16) + mt * 16 + ((lane >> 4) << 2);
    #pragma unroll
    for (int nt = 0; nt < NT; nt++) {
      const int col = n0 + wc * (NT * 16) + nt * 16 + (lane & 15);
      #pragma unroll
      for (int i = 0; i < 4; i++) {
        long r = m0 + rl0 + i;
        if (r < mstore) {
          float v = acc[mt][nt][i];
          long ci = coff + r * ldc + col;
          if constexpr (EPI == 0 || EPI == 6) ((float*)Cout)[ci] = v;
          else if constexpr (EPI == 1) ((unsigned short*)Cout)[ci] = f2bf(v);
          else if constexpr (EPI == 3) ((unsigned short*)Cout)[ci] = f2bf(v * zp[r]);
          else if constexpr (EPI == 5) {
            float o = v + aux[col];
            o = o > 0.f ? o : 0.f;
            ((float*)Cout)[ci] += o;
          }
        }
      }
    }
  }
  if constexpr (EPI == 6) {
    // per-row max over this block's cols -> atomicMax into kmax[batch*8+head]
    #pragma unroll
    for (int mt = 0; mt < MT; mt++) {
      #pragma unroll
      for (int i = 0; i < 4; i++) {
        float rm = -3.0e38f;
        #pragma unroll
        for (int nt = 0; nt < NT; nt++) rm = fmaxf(rm, acc[mt][nt][i]);
        #pragma unroll
        for (int s = 1; s < 16; s <<= 1) rm = fmaxf(rm, __shfl_xor(rm, s));
        long r = m0 + wr * (MT * 16) + mt * 16 + ((lane >> 4) << 2) + i;
        if ((lane & 15) == 0 && r < mstore)
          atomicMax(&((unsigned int*)offs)[batchv[r] * 8 + head], __float_as_uint(fmaxf(rm, 0.f)));
      }
    }
  }
}

// ===== small kernels =====

__global__ void k_fill(float* __restrict__ out, long n, float v) {
  long i = (long)blockIdx.x * 256 + threadIdx.x;
  if (i < n) out[i] = v;
}

__global__ void k_convert_x(const float* __restrict__ x, unsigned short* __restrict__ xb,
                            long ntotal, long nreal) {
  long i = ((long)blockIdx.x * 256 + threadIdx.x) * 4;
  if (i >= ntotal) return;
  u16x4 o;
  if (i < nreal) {
    f32x4 v = *(const f32x4*)(x + i);
    o[0] = f2bf(v[0]); o[1] = f2bf(v[1]); o[2] = f2bf(v[2]); o[3] = f2bf(v[3]);
  } else { o[0] = 0; o[1] = 0; o[2] = 0; o[3] = 0; }
  *(u16x4*)(xb + i) = o;
}

__global__ void k_transpose_w(const float* __restrict__ w, unsigned short* __restrict__ out) {
  int idx = blockIdx.x * 256 + threadIdx.x;
  if (idx >= 512 * 512) return;
  int n = idx >> 9, k = idx & 511;
  out[idx] = f2bf(w[k * 512 + n]);
}

__global__ void k_scale_copy_bf(const float* __restrict__ in, unsigned short* __restrict__ out,
                                int n, float scl) {
  int i = blockIdx.x * 256 + threadIdx.x;
  if (i < n) out[i] = f2bf(in[i] * scl);
}

__global__ void k_bn_stats(const float* __restrict__ x, float* __restrict__ s1,
                           float* __restrict__ s2, int N, int rpb) {
  int t = threadIdx.x;
  int r0 = blockIdx.x * rpb;
  int r1 = min(N, r0 + rpb);
  float a1 = 0, a2 = 0, b1 = 0, b2 = 0;
  for (int r = r0; r < r1; r++) {
    float va = x[(long)r * 512 + t];
    float vb = x[(long)r * 512 + t + 256];
    a1 += va; a2 += va * va; b1 += vb; b2 += vb * vb;
  }
  atomicAdd(&s1[t], a1); atomicAdd(&s2[t], a2);
  atomicAdd(&s1[t + 256], b1); atomicAdd(&s2[t + 256], b2);
}

__global__ void k_bn_final(const float* __restrict__ s1, const float* __restrict__ s2,
                           const float* __restrict__ g, const float* __restrict__ b,
                           float* __restrict__ a, float* __restrict__ c, float invN) {
  int t = threadIdx.x;
  float mu = s1[t] * invN;
  float var = s2[t] * invN - mu * mu;
  float inv = rsqrtf(var + 1e-5f);
  float av = g[t] * inv;
  a[t] = av;
  c[t] = b[t] - mu * av;
}

__global__ void k_deg_counts(const int* __restrict__ ed, unsigned int* __restrict__ deg,
                             const int* __restrict__ batch, unsigned int* __restrict__ counts,
                             long E, int N) {
  long i = (long)blockIdx.x * 256 + threadIdx.x;
  if (i < E) atomicAdd(&deg[ed[i]], 1u);
  if (i < N) atomicAdd(&counts[batch[i]], 1u);
}

__global__ void k_scan(const unsigned int* __restrict__ counts, unsigned int* __restrict__ offs) {
  if (threadIdx.x == 0) {
    unsigned int s = 0;
    for (int b = 0; b < 32; b++) { offs[b] = s; s += counts[b]; }
    offs[32] = s;
  }
}

// exclusive prefix scan of deg[N] -> rowstart[N+1]; single block, wave-shfl based
__global__ __launch_bounds__(1024) void k_scan_nodes(const unsigned int* __restrict__ deg,
                                                     unsigned int* __restrict__ rowstart, int N) {
  __shared__ unsigned int wsum[16];
  __shared__ unsigned int carry_s;
  int t = threadIdx.x, lane = t & 63, wid = t >> 6;
  if (t == 0) carry_s = 0;
  __syncthreads();
  for (int base = 0; base < N; base += 1024) {
    int i = base + t;
    unsigned int v = (i < N) ? deg[i] : 0;
    unsigned int sc = v;
    #pragma unroll
    for (int s = 1; s < 64; s <<= 1) {
      unsigned int u = __shfl_up(sc, s);
      if (lane >= s) sc += u;
    }
    if (lane == 63) wsum[wid] = sc;
    __syncthreads();
    unsigned int woff = 0, tot = 0;
    #pragma unroll
    for (int w = 0; w < 16; w++) { unsigned int s = wsum[w]; if (w < wid) woff += s; tot += s; }
    unsigned int carry = carry_s;
    if (i < N) rowstart[i] = carry + woff + sc - v;
    __syncthreads();
    if (t == 0) carry_s = carry + tot;
    __syncthreads();
  }
  if (threadIdx.x == 0) rowstart[N] = carry_s;
}

__global__ void k_csr_fill(const int* __restrict__ es, const int* __restrict__ ed,
                           const unsigned int* __restrict__ rowstart,
                           unsigned int* __restrict__ cursor, int* __restrict__ csr, long E) {
  long e = (long)blockIdx.x * 256 + threadIdx.x;
  if (e >= E) return;
  int d = ed[e];
  unsigned int slot = atomicAdd(&cursor[d], 1u);
  csr[rowstart[d] + slot] = es[e];
}

// gather-aggregate + deg-normalize + BN1 affine + bf16: conv_in[n] for n < Npad
__global__ __launch_bounds__(128) void k_gather(const int* __restrict__ csr,
                                                const unsigned int* __restrict__ rowstart,
                                                const float* __restrict__ x,
                                                const float* __restrict__ a1, const float* __restrict__ c1,
                                                unsigned short* __restrict__ conv_in, int N) {
  long n = blockIdx.x;
  int c = threadIdx.x * 4;
  u16x4 o; o[0] = 0; o[1] = 0; o[2] = 0; o[3] = 0;
  if (n < N) {
    unsigned int r0 = rowstart[n], r1 = rowstart[n + 1];
    if (r1 > r0) {
      f32x4 acc0 = {}, acc1 = {};
      unsigned int j = r0;
      for (; j + 2 <= r1; j += 2) {
        int s0 = csr[j], s1 = csr[j + 1];
        acc0 += *(const f32x4*)(x + (long)s0 * 512 + c);
        acc1 += *(const f32x4*)(x + (long)s1 * 512 + c);
      }
      if (j < r1) { int s0 = csr[j]; acc0 += *(const f32x4*)(x + (long)s0 * 512 + c); }
      f32x4 acc = acc0 + acc1;
      float inv = 1.f / (float)(r1 - r0);
      o[0] = f2bf(acc[0] * inv * a1[c + 0] + c1[c + 0]);
      o[1] = f2bf(acc[1] * inv * a1[c + 1] + c1[c + 1]);
      o[2] = f2bf(acc[2] * inv * a1[c + 2] + c1[c + 2]);
      o[3] = f2bf(acc[3] * inv * a1[c + 3] + c1[c + 3]);
    }
  }
  *(u16x4*)(conv_in + n * 512 + c) = o;
}

// diag[h*Npad + n] = 0.0625 * sum_d t[n,d]^2
__global__ void k_diag_all(const unsigned short* __restrict__ kvqh, float* __restrict__ diag,
                           long Npad, int N, int zoff) {
  int n = blockIdx.x * 4 + (threadIdx.x >> 6);
  int h = blockIdx.y;
  int lane = threadIdx.x & 63;
  if (n >= N) return;
  float v = bf2f(kvqh[((long)(zoff + h) * Npad + n) * 64 + lane]);
  float sq = v * v;
  for (int s = 1; s < 64; s <<= 1) sq += __shfl_xor(sq, s);
  if (lane == 0) diag[(long)h * Npad + n] = 0.0625f * sq;
}

__global__ void k_qf(const float* __restrict__ u, const float* __restrict__ dptr,
                     const float* __restrict__ kfsum, const int* __restrict__ batch,
                     unsigned short* __restrict__ qf, float* __restrict__ z, int h, int N) {
  int n = blockIdx.x * 4 + (threadIdx.x >> 6);
  int lane = threadIdx.x & 63;
  if (n >= N) return;
  float diag = dptr[n];
  f32x4 uv = *(const f32x4*)(u + (long)n * 256 + lane * 4);
  float m = fmaxf(fmaxf(uv[0], uv[1]), fmaxf(uv[2], uv[3]));
  for (int s = 1; s < 64; s <<= 1) m = fmaxf(m, __shfl_xor(m, s));
  f32x4 e;
  #pragma unroll
  for (int j = 0; j < 4; j++) e[j] = __expf(uv[j] - diag - m) * 0.0625f + 1e-6f;
  u16x4 o;
  #pragma unroll
  for (int j = 0; j < 4; j++) o[j] = f2bf(e[j]);
  *(u16x4*)(qf + (long)n * 256 + lane * 4) = o;
  const float* ks = kfsum + ((long)batch[n] * 8 + h) * 256;
  f32x4 k4 = *(const f32x4*)(ks + lane * 4);
  float dot = e[0] * k4[0] + e[1] * k4[1] + e[2] * k4[2] + e[3] * k4[3];
  for (int s = 1; s < 64; s <<= 1) dot += __shfl_xor(dot, s);
  if (lane == 0) z[n] = 1.f / (dot + 1e-6f);
}

// kvT[b][h][d][m] += sum_i kf[i][m]*v[i][d]; kfsum[b][h][m] += sum_i kf[i][m]
// kf computed inline: exp(u - diag - kmax) / 16 + 1e-6   (f32, better than round-2 bf16)
__global__ __launch_bounds__(256) void k_kv(const float* __restrict__ u,
                                            const float* __restrict__ dptr,
                                            const unsigned int* __restrict__ kmax,
                                            const unsigned short* __restrict__ vh,
                                            const unsigned int* __restrict__ offs,
                                            float* __restrict__ kvT, float* __restrict__ kfsum, int h) {
  int b = blockIdx.y;
  unsigned int off = offs[b];
  int nb = (int)(offs[b + 1] - off);
  int start = blockIdx.x * 256;
  if (start >= nb) return;
  int cnt = min(256, nb - start);
  float km = __uint_as_float(kmax[b * 8 + h]);
  __shared__ float kfs[16][256];
  __shared__ float vs[16][64];
  int tid = threadIdx.x;
  int mg = tid & 63, dg = tid >> 6;  // m0 = mg*4, d0 = dg*16
  f32x4 acc[4][4] = {};
  f32x4 sacc = {};
  for (int g0 = 0; g0 < cnt; g0 += 16) {
    int nv = min(16, cnt - g0);
    #pragma unroll
    for (int ch = tid; ch < 16 * 64; ch += 256) {
      int r = ch >> 6, c4 = (ch & 63) * 4;
      if (r < nv) {
        long node = (long)(off + start + g0 + r);
        float dgv = dptr[node];
        f32x4 uv = *(const f32x4*)(u + node * 256 + c4);
        f32x4 e;
        #pragma unroll
        for (int j = 0; j < 4; j++) e[j] = __expf(uv[j] - dgv - km) * 0.0625f + 1e-6f;
        *(f32x4*)(&kfs[r][c4]) = e;
      }
    }
    {
      int r = tid >> 4, c4 = (tid & 15) * 4;
      if (r < nv) {
        u16x4 v = *(const u16x4*)(vh + (long)(off + start + g0 + r) * 64 + c4);
        #pragma unroll
        for (int j = 0; j < 4; j++) vs[r][c4 + j] = bf2f(v[j]);
      }
    }
    __syncthreads();
    for (int r = 0; r < nv; r++) {
      f32x4 kfv = *(const f32x4*)(&kfs[r][mg * 4]);
      #pragma unroll
      for (int jq = 0; jq < 4; jq++) {
        f32x4 vv = *(const f32x4*)(&vs[r][dg * 16 + jq * 4]);
        #pragma unroll
        for (int mi = 0; mi < 4; mi++) acc[mi][jq] += kfv[mi] * vv;
      }
      if (dg == 0) sacc += kfv;
    }
    __syncthreads();
  }
  long base = ((long)b * 8 + h) * 16384;
  #pragma unroll
  for (int jq = 0; jq < 4; jq++)
    #pragma unroll
    for (int dj = 0; dj < 4; dj++) {
      int d = dg * 16 + jq * 4 + dj;
      #pragma unroll
      for (int mi = 0; mi < 4; mi++)
        atomicAdd(&kvT[base + (long)d * 256 + mg * 4 + mi], acc[mi][jq][dj]);
    }
  if (dg == 0) {
    long sb = ((long)b * 8 + h) * 256 + mg * 4;
    #pragma unroll
    for (int mi = 0; mi < 4; mi++) atomicAdd(&kfsum[sb + mi], sacc[mi]);
  }
}

__global__ void k_f32_to_bf16_4(const float* __restrict__ in, unsigned short* __restrict__ out, long n) {
  long i = ((long)blockIdx.x * 256 + threadIdx.x) * 4;
  if (i >= n) return;
  f32x4 v = *(const f32x4*)(in + i);
  u16x4 o;
  o[0] = f2bf(v[0]); o[1] = f2bf(v[1]); o[2] = f2bf(v[2]); o[3] = f2bf(v[3]);
  *(u16x4*)(out + i) = o;
}

// out += x (residual), accumulate BN2 stats
__global__ void k_sum_x_stats(const float* __restrict__ x, float* __restrict__ y,
                              float* __restrict__ s1, float* __restrict__ s2, int N, int rpb) {
  int t = threadIdx.x;
  int r0 = blockIdx.x * rpb;
  int r1 = min(N, r0 + rpb);
  float a1 = 0, a2 = 0, b1 = 0, b2 = 0;
  for (int r = r0; r < r1; r++) {
    long ia = (long)r * 512 + t;
    long ib = ia + 256;
    float va = x[ia] + y[ia];
    float vb = x[ib] + y[ib];
    y[ia] = va; y[ib] = vb;
    a1 += va; a2 += va * va; b1 += vb; b2 += vb * vb;
  }
  atomicAdd(&s1[t], a1); atomicAdd(&s2[t], a2);
  atomicAdd(&s1[t + 256], b1); atomicAdd(&s2[t + 256], b2);
}

__global__ void k_bn_apply(float* __restrict__ y, const float* __restrict__ a,
                           const float* __restrict__ c, long total) {
  long i4 = ((long)blockIdx.x * 256 + threadIdx.x) * 4;
  if (i4 >= total) return;
  int col = (int)(i4 & 511);
  f32x4 v = *(const f32x4*)(y + i4);
  #pragma unroll
  for (int j = 0; j < 4; j++) v[j] = v[j] * a[col + j] + c[col + j];
  *(f32x4*)(y + i4) = v;
}

// ===== host =====

extern "C" void kernel_launch(void* const* d_in, const int* in_sizes, int n_in,
                              void* d_out, int out_size, void* d_ws, size_t ws_size,
                              hipStream_t stream) {
  (void)n_in; (void)out_size;
  const float* x = (const float*)d_in[0];
  const int* batch = (const int*)d_in[1];
  const int* eidx = (const int*)d_in[2];
  const float* n1g = (const float*)d_in[3];
  const float* n1b = (const float*)d_in[4];
  const float* n2g = (const float*)d_in[5];
  const float* n2b = (const float*)d_in[6];
  const float* wconv = (const float*)d_in[7];
  const float* bconv = (const float*)d_in[8];
  const float* wq = (const float*)d_in[9];
  const float* wk = (const float*)d_in[10];
  const float* wv = (const float*)d_in[11];
  const float* wo = (const float*)d_in[12];
  const float* proj = (const float*)d_in[13];

  const int N = in_sizes[1];
  const long E = in_sizes[2] / 2;
  const long Npad = CDIV(N, 128) * 128;
  const int Mb = (int)(Npad / 128);
  const int* es = eidx;
  const int* ed = eidx + E;
  float* out = (float*)d_out;

  char* p = (char*)d_ws;
  auto alloc = [&](size_t bytes) -> char* {
    char* r = p;
    p += (bytes + 255) & ~(size_t)255;
    return r;
  };
  float*          ubuf = (float*)alloc((size_t)Npad * 256 * 4);               // 49.8 MB
  unsigned short* kvqh = (unsigned short*)alloc((size_t)24 * Npad * 64 * 2);  // 37.3 MB (q:0-7,k:8-15,v:16-23)
  unsigned short* qf   = (unsigned short*)alloc((size_t)Npad * 256 * 2);      // 24.9 MB
  unsigned short* xbf  = (unsigned short*)alloc((size_t)Npad * 512 * 2);      // 49.8 MB (-> attn_all -> conv_in)
  float*          kvT_f = (float*)alloc((size_t)32 * 8 * 16384 * 4);          // 16.8 MB
  unsigned short* kvT_b = (unsigned short*)alloc((size_t)32 * 8 * 16384 * 2); // 8.4 MB
  float*          diag  = (float*)alloc((size_t)8 * Npad * 4);                // 1.56 MB
  unsigned short* wqkv_t = (unsigned short*)alloc((size_t)24 * 64 * 512 * 2);
  unsigned short* wconv_t = (unsigned short*)alloc((size_t)512 * 512 * 2);
  unsigned short* wo_t   = (unsigned short*)alloc((size_t)512 * 512 * 2);
  unsigned short* proj_s = (unsigned short*)alloc((size_t)256 * 64 * 2);
  float* bn1_acc = (float*)alloc(1024 * 4);
  float* bn1_ac  = (float*)alloc(1024 * 4);
  float* bn2_acc = (float*)alloc(1024 * 4);
  float* bn2_ac  = (float*)alloc(1024 * 4);
  unsigned int* deg      = (unsigned int*)alloc((size_t)N * 4);
  unsigned int* counts   = (unsigned int*)alloc(32 * 4);
  unsigned int* offs     = (unsigned int*)alloc(33 * 4);
  unsigned int* kmax     = (unsigned int*)alloc(32 * 8 * 4);
  float* kfsum = (float*)alloc((size_t)32 * 8 * 256 * 4);
  float* zbuf  = (float*)alloc((size_t)N * 4);
  unsigned int* rowstart = (unsigned int*)alloc((size_t)(N + 1) * 4);
  unsigned int* cursor   = (unsigned int*)alloc((size_t)N * 4);
  int* csr               = (int*)alloc((size_t)E * 4);
  size_t required = (size_t)(p - (char*)d_ws);
  if (required > ws_size) {
    k_fill<<<(int)CDIV((long)N * 512, 256), 256, 0, stream>>>(
        out, (long)N * 512, 1.0e6f + (float)(ws_size >> 20));
    return;
  }
  unsigned short* attn_all = xbf;
  unsigned short* conv_in  = xbf;

  // ---- zero accumulators (ws is not re-poisoned between replays) ----
  hipMemsetAsync(deg, 0, (size_t)N * 4, stream);
  hipMemsetAsync(cursor, 0, (size_t)N * 4, stream);
  hipMemsetAsync(counts, 0, 32 * 4, stream);
  hipMemsetAsync(kvT_f, 0, (size_t)32 * 8 * 16384 * 4, stream);
  hipMemsetAsync(kfsum, 0, (size_t)32 * 8 * 256 * 4, stream);
  hipMemsetAsync(kmax, 0, 32 * 8 * 4, stream);
  hipMemsetAsync(bn1_acc, 0, 1024 * 4, stream);
  hipMemsetAsync(bn2_acc, 0, 1024 * 4, stream);

  // ---- prep ----
  k_convert_x<<<(int)CDIV(Npad * 512 / 4, 256), 256, 0, stream>>>(x, xbf, Npad * 512, (long)N * 512);
  k_transpose_w<<<CDIV(512 * 512, 256), 256, 0, stream>>>(wq, wqkv_t);
  k_transpose_w<<<CDIV(512 * 512, 256), 256, 0, stream>>>(wk, wqkv_t + 8 * 64 * 512);
  k_transpose_w<<<CDIV(512 * 512, 256), 256, 0, stream>>>(wv, wqkv_t + 16 * 64 * 512);
  k_transpose_w<<<CDIV(512 * 512, 256), 256, 0, stream>>>(wconv, wconv_t);
  k_transpose_w<<<CDIV(512 * 512, 256), 256, 0, stream>>>(wo, wo_t);
  k_scale_copy_bf<<<CDIV(256 * 64, 256), 256, 0, stream>>>(proj, proj_s, 256 * 64, 0.35355339059327373f);

  int rpb = CDIV(N, 1024);
  k_bn_stats<<<1024, 256, 0, stream>>>(x, bn1_acc, bn1_acc + 512, N, rpb);
  k_bn_final<<<1, 512, 0, stream>>>(bn1_acc, bn1_acc + 512, n1g, n1b, bn1_ac, bn1_ac + 512, 1.f / N);
  k_deg_counts<<<(int)CDIV(E, 256), 256, 0, stream>>>(ed, deg, batch, counts, E, N);
  k_scan<<<1, 64, 0, stream>>>(counts, offs);
  k_scan_nodes<<<1, 1024, 0, stream>>>(deg, rowstart, N);
  k_csr_fill<<<(int)CDIV(E, 256), 256, 0, stream>>>(es, ed, rowstart, cursor, csr, E);

  // ---- per-head q/k/v projections, one z-batched GEMM (z = 24 head-tensors) ----
  gemm_bt<128, 64, 2, 2, 1><<<dim3(1, Mb, 24), 256, 0, stream>>>(
      xbf, wqkv_t, kvqh, nullptr, nullptr, nullptr,
      512, 512, 512, 64, 0, (long)64 * 512, (long)Npad * 64, (int)Npad, 0);

  // ---- keys pass: u-GEMM (with fused kmax) then fused-kf kv accumulation ----
  k_diag_all<<<dim3(CDIV(N, 4), 8), 256, 0, stream>>>(kvqh, diag, Npad, N, 8);
  for (int h = 0; h < 8; h++) {
    const unsigned short* kh = kvqh + (long)(8 + h) * Npad * 64;
    const unsigned short* vh = kvqh + (long)(16 + h) * Npad * 64;
    gemm_bt<128, 128, 2, 2, 6><<<dim3(2, Mb), 256, 0, stream>>>(
        kh, proj_s, ubuf, nullptr, kmax, batch, 64, 64, 64, 256, 0, 0, 0, N, h);
    k_kv<<<dim3(8, 32), 256, 0, stream>>>(ubuf, diag + (long)h * Npad, kmax, vh, offs, kvT_f, kfsum, h);
  }
  k_f32_to_bf16_4<<<CDIV((long)32 * 8 * 16384 / 4, 256), 256, 0, stream>>>(
      kvT_f, kvT_b, (long)32 * 8 * 16384);

  // ---- queries pass ----
  k_diag_all<<<dim3(CDIV(N, 4), 8), 256, 0, stream>>>(kvqh, diag, Npad, N, 0);
  for (int h = 0; h < 8; h++) {
    const unsigned short* qh = kvqh + (long)h * Npad * 64;
    gemm_bt<128, 128, 2, 2, 0><<<dim3(2, Mb), 256, 0, stream>>>(
        qh, proj_s, ubuf, nullptr, nullptr, nullptr, 64, 64, 64, 256, 0, 0, 0, N, 0);
    k_qf<<<CDIV(N, 4), 256, 0, stream>>>(ubuf, diag + (long)h * Npad, kfsum, batch, qf, zbuf, h, N);
    gemm_bt<256, 64, 4, 1, 3><<<dim3(1, 8, 32), 256, 0, stream>>>(
        qf, kvT_b + (long)h * 16384, attn_all + h * 64, zbuf, offs, nullptr,
        256, 256, 256, 512, 0, (long)8 * 16384, 0, 1 << 30, 0);
  }

  // ---- output projection (full overwrite of out) ----
  gemm_bt<128, 128, 2, 2, 0><<<dim3(4, Mb), 256, 0, stream>>>(
      attn_all, wo_t, out, nullptr, nullptr, nullptr, 512, 512, 512, 512, 0, 0, 0, N, 0);

  // ---- GNN conv path: CSR gather (fused BN1-affine + normalize + bf16) ----
  k_gather<<<(int)Npad, 128, 0, stream>>>(csr, rowstart, x, bn1_ac, bn1_ac + 512, conv_in, N);
  gemm_bt<128, 128, 2, 2, 5><<<dim3(4, Mb), 256, 0, stream>>>(
      conv_in, wconv_t, out, bconv, nullptr, nullptr, 512, 512, 512, 512, 0, 0, 0, N, 0);

  // ---- residual + BN2 ----
  k_sum_x_stats<<<1024, 256, 0, stream>>>(x, out, bn2_acc, bn2_acc + 512, N, rpb);
  k_bn_final<<<1, 512, 0, stream>>>(bn2_acc, bn2_acc + 512, n2g, n2b, bn2_ac, bn2_ac + 512, 1.f / N);
  k_bn_apply<<<(int)CDIV((long)N * 512 / 4, 256), 256, 0, stream>>>(out, bn2_ac, bn2_ac + 512, (long)N * 512);
}

// Round 4
// 2585.560 us; speedup vs baseline: 2.3991x; 1.7409x over previous
//
#include <hip/hip_runtime.h>
#include <stdint.h>

#define CDIV(a,b) (((a)+(b)-1)/(b))

typedef __attribute__((ext_vector_type(4))) float f32x4;
typedef __attribute__((ext_vector_type(8))) short s16x8;
typedef __attribute__((ext_vector_type(8))) unsigned short u16x8;
typedef __attribute__((ext_vector_type(4))) unsigned short u16x4;

__device__ __forceinline__ float bf2f(unsigned short u) {
  union { unsigned int i; float f; } c; c.i = ((unsigned int)u) << 16; return c.f;
}
__device__ __forceinline__ unsigned short f2bf(float f) {
  union { float f; unsigned int i; } c; c.f = f;
  unsigned int u = c.i;
  u += 0x7fffu + ((u >> 16) & 1u);
  return (unsigned short)(u >> 16);
}

// ===== GEMM: C[M,N] = A(bf16)[M,K] * B(bf16)[N,K]^T =====
// EPI: 0 = f32 store, 5 = f32 += relu(acc + aux[col]),
//      6 = f32 store of (acc - diag[row]) + per-graph row-max(u) atomicMax (kmax via offs ptr),
//          diag computed in-kernel from A fragments (0.0625 * sum_k a^2)
//      7 = bf16 store remapped col -> (z = col>>6, c = col&63): C[z*zsC + r*64 + c]
template<int BM, int BN, int WM, int WN, int EPI>
__global__ __launch_bounds__(256) void gemm_bt(
    const unsigned short* __restrict__ A, const unsigned short* __restrict__ B,
    void* __restrict__ Cout, const float* __restrict__ aux,
    const unsigned int* __restrict__ offs, const int* __restrict__ batchv,
    int K, int lda, int ldb, int ldc,
    long zsC, int Mstore, int head)
{
  constexpr int MT = BM / (WM * 16);
  constexpr int NT = BN / (WN * 16);
  constexpr int LDT = 40;  // padded LDS row stride (ushorts)
  __shared__ unsigned short As[BM * LDT];
  __shared__ unsigned short Bs[BN * LDT];
  const int tid = threadIdx.x, wid = tid >> 6, lane = tid & 63;
  const int wr = wid / WN, wc = wid % WN;
  long m0 = (long)blockIdx.y * BM;
  const int n0 = blockIdx.x * BN;
  f32x4 acc[MT][NT] = {};
  float dsum[MT];
  #pragma unroll
  for (int mt = 0; mt < MT; mt++) dsum[mt] = 0.f;
  for (int k0 = 0; k0 < K; k0 += 32) {
    #pragma unroll
    for (int c = tid; c < BM * 4; c += 256) {
      int row = c >> 2, c8 = (c & 3) * 8;
      *(u16x8*)(&As[row * LDT + c8]) = *(const u16x8*)(A + (m0 + row) * lda + k0 + c8);
    }
    #pragma unroll
    for (int c = tid; c < BN * 4; c += 256) {
      int row = c >> 2, c8 = (c & 3) * 8;
      *(u16x8*)(&Bs[row * LDT + c8]) = *(const u16x8*)(B + (long)(n0 + row) * ldb + k0 + c8);
    }
    __syncthreads();
    s16x8 af[MT], bfv[NT];
    #pragma unroll
    for (int mt = 0; mt < MT; mt++)
      af[mt] = *(const s16x8*)(&As[(wr * MT * 16 + mt * 16 + (lane & 15)) * LDT + ((lane >> 4) * 8)]);
    #pragma unroll
    for (int nt = 0; nt < NT; nt++)
      bfv[nt] = *(const s16x8*)(&Bs[(wc * NT * 16 + nt * 16 + (lane & 15)) * LDT + ((lane >> 4) * 8)]);
    if constexpr (EPI == 6) {
      if (wid == 0) {
        #pragma unroll
        for (int mt = 0; mt < MT; mt++)
          #pragma unroll
          for (int j = 0; j < 8; j++) {
            float a = bf2f((unsigned short)af[mt][j]);
            dsum[mt] += a * a;
          }
      }
    }
    #pragma unroll
    for (int mt = 0; mt < MT; mt++)
      #pragma unroll
      for (int nt = 0; nt < NT; nt++)
        acc[mt][nt] = __builtin_amdgcn_mfma_f32_16x16x32_bf16(af[mt], bfv[nt], acc[mt][nt], 0, 0, 0);
    __syncthreads();
  }
  if constexpr (EPI == 6) {
    // WM==1 assumed: all waves share rows; wave 0 computed dsum
    __shared__ float sdiag[BM];
    __shared__ float smax[WN][BM];
    if (wid == 0) {
      #pragma unroll
      for (int mt = 0; mt < MT; mt++) {
        float s = dsum[mt];
        s += __shfl_xor(s, 16); s += __shfl_xor(s, 32);
        if (lane < 16) sdiag[mt * 16 + lane] = 0.0625f * s;
      }
    }
    #pragma unroll
    for (int mt = 0; mt < MT; mt++)
      #pragma unroll
      for (int i = 0; i < 4; i++) {
        float rm = -3.0e38f;
        #pragma unroll
        for (int nt = 0; nt < NT; nt++) rm = fmaxf(rm, acc[mt][nt][i]);
        rm = fmaxf(rm, __shfl_xor(rm, 1)); rm = fmaxf(rm, __shfl_xor(rm, 2));
        rm = fmaxf(rm, __shfl_xor(rm, 4)); rm = fmaxf(rm, __shfl_xor(rm, 8));
        if ((lane & 15) == 0) smax[wc][mt * 16 + ((lane >> 4) << 2) + i] = rm;
      }
    __syncthreads();
    #pragma unroll
    for (int mt = 0; mt < MT; mt++) {
      const int rl0 = mt * 16 + ((lane >> 4) << 2);
      #pragma unroll
      for (int nt = 0; nt < NT; nt++) {
        const int col = n0 + wc * (NT * 16) + nt * 16 + (lane & 15);
        #pragma unroll
        for (int i = 0; i < 4; i++) {
          long r = m0 + rl0 + i;
          if (r < Mstore) ((float*)Cout)[r * ldc + col] = acc[mt][nt][i] - sdiag[rl0 + i];
        }
      }
    }
    if (tid < BM) {
      long r = m0 + tid;
      if (r < Mstore) {
        float mx = smax[0][tid];
        #pragma unroll
        for (int w = 1; w < WN; w++) mx = fmaxf(mx, smax[w][tid]);
        atomicMax(&((unsigned int*)offs)[batchv[r] * 8 + head], __float_as_uint(fmaxf(mx, 0.f)));
      }
    }
  } else {
    #pragma unroll
    for (int mt = 0; mt < MT; mt++) {
      const int rl0 = wr * (MT * 16) + mt * 16 + ((lane >> 4) << 2);
      #pragma unroll
      for (int nt = 0; nt < NT; nt++) {
        const int col = n0 + wc * (NT * 16) + nt * 16 + (lane & 15);
        #pragma unroll
        for (int i = 0; i < 4; i++) {
          long r = m0 + rl0 + i;
          if (r < Mstore) {
            float v = acc[mt][nt][i];
            if constexpr (EPI == 0) ((float*)Cout)[r * ldc + col] = v;
            else if constexpr (EPI == 5) {
              float o = v + aux[col];
              o = o > 0.f ? o : 0.f;
              ((float*)Cout)[r * ldc + col] += o;
            } else if constexpr (EPI == 7) {
              ((unsigned short*)Cout)[(long)(col >> 6) * zsC + r * 64 + (col & 63)] = f2bf(v);
            }
          }
        }
      }
    }
  }
}

// ===== fused query-side flash kernel =====
// per block: 64 rows of one (graph b, head h): u = q@proj^T (MFMA), diag from A frags,
// rowmax, qf = exp(u - diag - rowmax)*0.0625 + 1e-6 -> LDS bf16, z = 1/(qf . kfsum + eps),
// attn = (qf @ kvT^T) * z -> bf16 store
__global__ __launch_bounds__(256) void k_qflash(
    const unsigned short* __restrict__ qh_all, const unsigned short* __restrict__ projb,
    const unsigned short* __restrict__ kvTb, const float* __restrict__ kfsum,
    const unsigned int* __restrict__ offs, unsigned short* __restrict__ attn, long Npad) {
  constexpr int LDT = 40, QLDT = 264;
  __shared__ unsigned short As[64 * LDT];
  __shared__ unsigned short Bs[256 * LDT];
  __shared__ unsigned short qfs[64 * QLDT];
  __shared__ float skf[256];
  __shared__ float sdiag[64];
  __shared__ float smax[4][64];
  __shared__ float szp[4][64];
  const int tid = threadIdx.x, wid = tid >> 6, lane = tid & 63;
  const int b = blockIdx.y, h = blockIdx.z;
  const unsigned int off = offs[b];
  const int nb = (int)(offs[b + 1] - off);
  const int m0 = blockIdx.x * 64;
  if (m0 >= nb) return;
  const unsigned short* A = qh_all + ((long)h * Npad + off + m0) * 64;
  skf[tid] = kfsum[((long)b * 8 + h) * 256 + tid];
  f32x4 acc[4][4] = {};
  float dsum[4] = {0.f, 0.f, 0.f, 0.f};
  for (int k0 = 0; k0 < 64; k0 += 32) {
    { int c = tid & 255; int row = c >> 2, c8 = (c & 3) * 8;
      *(u16x8*)(&As[row * LDT + c8]) = *(const u16x8*)(A + (long)row * 64 + k0 + c8); }
    #pragma unroll
    for (int c = tid; c < 1024; c += 256) {
      int row = c >> 2, c8 = (c & 3) * 8;
      *(u16x8*)(&Bs[row * LDT + c8]) = *(const u16x8*)(projb + (long)row * 64 + k0 + c8);
    }
    __syncthreads();
    s16x8 af[4], bfv[4];
    #pragma unroll
    for (int mt = 0; mt < 4; mt++)
      af[mt] = *(const s16x8*)(&As[(mt * 16 + (lane & 15)) * LDT + ((lane >> 4) * 8)]);
    #pragma unroll
    for (int nt = 0; nt < 4; nt++)
      bfv[nt] = *(const s16x8*)(&Bs[(wid * 64 + nt * 16 + (lane & 15)) * LDT + ((lane >> 4) * 8)]);
    if (wid == 0) {
      #pragma unroll
      for (int mt = 0; mt < 4; mt++)
        #pragma unroll
        for (int j = 0; j < 8; j++) {
          float a = bf2f((unsigned short)af[mt][j]);
          dsum[mt] += a * a;
        }
    }
    #pragma unroll
    for (int mt = 0; mt < 4; mt++)
      #pragma unroll
      for (int nt = 0; nt < 4; nt++)
        acc[mt][nt] = __builtin_amdgcn_mfma_f32_16x16x32_bf16(af[mt], bfv[nt], acc[mt][nt], 0, 0, 0);
    __syncthreads();
  }
  if (wid == 0) {
    #pragma unroll
    for (int mt = 0; mt < 4; mt++) {
      float s = dsum[mt];
      s += __shfl_xor(s, 16); s += __shfl_xor(s, 32);
      if (lane < 16) sdiag[mt * 16 + lane] = 0.0625f * s;
    }
  }
  #pragma unroll
  for (int mt = 0; mt < 4; mt++)
    #pragma unroll
    for (int i = 0; i < 4; i++) {
      float rm = fmaxf(fmaxf(acc[mt][0][i], acc[mt][1][i]), fmaxf(acc[mt][2][i], acc[mt][3][i]));
      rm = fmaxf(rm, __shfl_xor(rm, 1)); rm = fmaxf(rm, __shfl_xor(rm, 2));
      rm = fmaxf(rm, __shfl_xor(rm, 4)); rm = fmaxf(rm, __shfl_xor(rm, 8));
      if ((lane & 15) == 0) smax[wid][mt * 16 + ((lane >> 4) << 2) + i] = rm;
    }
  __syncthreads();
  #pragma unroll
  for (int mt = 0; mt < 4; mt++)
    #pragma unroll
    for (int i = 0; i < 4; i++) {
      int row = mt * 16 + ((lane >> 4) << 2) + i;
      float rm = fmaxf(fmaxf(smax[0][row], smax[1][row]), fmaxf(smax[2][row], smax[3][row]));
      float dg = sdiag[row];
      float zp = 0.f;
      #pragma unroll
      for (int nt = 0; nt < 4; nt++) {
        int col = wid * 64 + nt * 16 + (lane & 15);
        float e = __expf(acc[mt][nt][i] - dg - rm) * 0.0625f + 1e-6f;
        qfs[row * QLDT + col] = f2bf(e);
        zp += e * skf[col];
      }
      zp += __shfl_xor(zp, 1); zp += __shfl_xor(zp, 2);
      zp += __shfl_xor(zp, 4); zp += __shfl_xor(zp, 8);
      if ((lane & 15) == 0) szp[wid][row] = zp;
    }
  __syncthreads();
  const unsigned short* kvb = kvTb + ((long)b * 8 + h) * 16384;
  f32x4 acc2[4] = {};
  #pragma unroll
  for (int ks = 0; ks < 8; ks++) {
    s16x8 aq = *(const s16x8*)(&qfs[(wid * 16 + (lane & 15)) * QLDT + ks * 32 + ((lane >> 4) * 8)]);
    #pragma unroll
    for (int ntd = 0; ntd < 4; ntd++) {
      s16x8 bk = *(const s16x8*)(kvb + (long)(ntd * 16 + (lane & 15)) * 256 + ks * 32 + ((lane >> 4) * 8));
      acc2[ntd] = __builtin_amdgcn_mfma_f32_16x16x32_bf16(aq, bk, acc2[ntd], 0, 0, 0);
    }
  }
  #pragma unroll
  for (int ntd = 0; ntd < 4; ntd++)
    #pragma unroll
    for (int i = 0; i < 4; i++) {
      int row = wid * 16 + ((lane >> 4) << 2) + i;
      if (m0 + row < nb) {
        float zr = 1.f / (szp[0][row] + szp[1][row] + szp[2][row] + szp[3][row] + 1e-6f);
        attn[(long)(off + m0 + row) * 512 + h * 64 + ntd * 16 + (lane & 15)] = f2bf(acc2[ntd][i] * zr);
      }
    }
}

// ===== small kernels =====

__global__ void k_fill(float* __restrict__ out, long n, float v) {
  long i = (long)blockIdx.x * 256 + threadIdx.x;
  if (i < n) out[i] = v;
}

__global__ void k_convert_x(const float* __restrict__ x, unsigned short* __restrict__ xb,
                            long ntotal, long nreal) {
  long i = ((long)blockIdx.x * 256 + threadIdx.x) * 4;
  if (i >= ntotal) return;
  u16x4 o;
  if (i < nreal) {
    f32x4 v = *(const f32x4*)(x + i);
    o[0] = f2bf(v[0]); o[1] = f2bf(v[1]); o[2] = f2bf(v[2]); o[3] = f2bf(v[3]);
  } else { o[0] = 0; o[1] = 0; o[2] = 0; o[3] = 0; }
  *(u16x4*)(xb + i) = o;
}

// 5 weight transposes in one launch: out layout [which][out_col][in_k]
__global__ void k_transall(const float* __restrict__ w0, const float* __restrict__ w1,
                           const float* __restrict__ w2, const float* __restrict__ w3,
                           const float* __restrict__ w4, unsigned short* __restrict__ out) {
  long idx = (long)blockIdx.x * 256 + threadIdx.x;
  if (idx >= (5L << 18)) return;
  int which = (int)(idx >> 18);
  int r = (int)(idx & 262143);
  int n = r >> 9, k = r & 511;
  const float* w = which == 0 ? w0 : which == 1 ? w1 : which == 2 ? w2 : which == 3 ? w3 : w4;
  out[idx] = f2bf(w[k * 512 + n]);
}

__global__ void k_scale_copy_bf(const float* __restrict__ in, unsigned short* __restrict__ out,
                                int n, float scl) {
  int i = blockIdx.x * 256 + threadIdx.x;
  if (i < n) out[i] = f2bf(in[i] * scl);
}

__global__ void k_bn_stats(const float* __restrict__ x, float* __restrict__ s1,
                           float* __restrict__ s2, int N, int rpb) {
  int t = threadIdx.x;
  int r0 = blockIdx.x * rpb;
  int r1 = min(N, r0 + rpb);
  float a1 = 0, a2 = 0, b1 = 0, b2 = 0;
  for (int r = r0; r < r1; r++) {
    float va = x[(long)r * 512 + t];
    float vb = x[(long)r * 512 + t + 256];
    a1 += va; a2 += va * va; b1 += vb; b2 += vb * vb;
  }
  atomicAdd(&s1[t], a1); atomicAdd(&s2[t], a2);
  atomicAdd(&s1[t + 256], b1); atomicAdd(&s2[t + 256], b2);
}

__global__ void k_bn_final(const float* __restrict__ s1, const float* __restrict__ s2,
                           const float* __restrict__ g, const float* __restrict__ b,
                           float* __restrict__ a, float* __restrict__ c, float invN) {
  int t = threadIdx.x;
  float mu = s1[t] * invN;
  float var = s2[t] * invN - mu * mu;
  float inv = rsqrtf(var + 1e-5f);
  float av = g[t] * inv;
  a[t] = av;
  c[t] = b[t] - mu * av;
}

__global__ void k_deg(const int* __restrict__ ed, unsigned int* __restrict__ deg, long E) {
  long i = (long)blockIdx.x * 256 + threadIdx.x;
  if (i < E) atomicAdd(&deg[ed[i]], 1u);
}

// graph offsets from sorted batch via boundary detection (no atomics)
__global__ void k_offs(const int* __restrict__ batch, unsigned int* __restrict__ offs, int N) {
  int i = blockIdx.x * 256 + threadIdx.x;
  if (i >= N) return;
  int b = batch[i];
  if (i == 0) { for (int bb = 0; bb <= b; bb++) offs[bb] = 0; }
  else {
    int pb = batch[i - 1];
    if (pb != b) for (int bb = pb + 1; bb <= b; bb++) offs[bb] = i;
  }
  if (i == N - 1) { for (int bb = b + 1; bb <= 32; bb++) offs[bb] = N; }
}

// exclusive prefix scan of deg[N] -> rowstart[N+1]; single block, wave-shfl based
__global__ __launch_bounds__(1024) void k_scan_nodes(const unsigned int* __restrict__ deg,
                                                     unsigned int* __restrict__ rowstart, int N) {
  __shared__ unsigned int wsum[16];
  __shared__ unsigned int carry_s;
  int t = threadIdx.x, lane = t & 63, wid = t >> 6;
  if (t == 0) carry_s = 0;
  __syncthreads();
  for (int base = 0; base < N; base += 1024) {
    int i = base + t;
    unsigned int v = (i < N) ? deg[i] : 0;
    unsigned int sc = v;
    #pragma unroll
    for (int s = 1; s < 64; s <<= 1) {
      unsigned int u = __shfl_up(sc, s);
      if (lane >= s) sc += u;
    }
    if (lane == 63) wsum[wid] = sc;
    __syncthreads();
    unsigned int woff = 0, tot = 0;
    #pragma unroll
    for (int w = 0; w < 16; w++) { unsigned int s = wsum[w]; if (w < wid) woff += s; tot += s; }
    unsigned int carry = carry_s;
    if (i < N) rowstart[i] = carry + woff + sc - v;
    __syncthreads();
    if (t == 0) carry_s = carry + tot;
    __syncthreads();
  }
  if (threadIdx.x == 0) rowstart[N] = carry_s;
}

__global__ void k_csr_fill(const int* __restrict__ es, const int* __restrict__ ed,
                           const unsigned int* __restrict__ rowstart,
                           unsigned int* __restrict__ cursor, int* __restrict__ csr, long E) {
  long e = (long)blockIdx.x * 256 + threadIdx.x;
  if (e >= E) return;
  int d = ed[e];
  unsigned int slot = atomicAdd(&cursor[d], 1u);
  csr[rowstart[d] + slot] = es[e];
}

// gather-aggregate + deg-normalize + BN1 affine + bf16
__global__ __launch_bounds__(128) void k_gather(const int* __restrict__ csr,
                                                const unsigned int* __restrict__ rowstart,
                                                const float* __restrict__ x,
                                                const float* __restrict__ a1, const float* __restrict__ c1,
                                                unsigned short* __restrict__ conv_in, int N) {
  long n = blockIdx.x;
  int c = threadIdx.x * 4;
  u16x4 o; o[0] = 0; o[1] = 0; o[2] = 0; o[3] = 0;
  if (n < N) {
    unsigned int r0 = rowstart[n], r1 = rowstart[n + 1];
    if (r1 > r0) {
      f32x4 acc0 = {}, acc1 = {};
      unsigned int j = r0;
      for (; j + 2 <= r1; j += 2) {
        int s0 = csr[j], s1 = csr[j + 1];
        acc0 += *(const f32x4*)(x + (long)s0 * 512 + c);
        acc1 += *(const f32x4*)(x + (long)s1 * 512 + c);
      }
      if (j < r1) { int s0 = csr[j]; acc0 += *(const f32x4*)(x + (long)s0 * 512 + c); }
      f32x4 acc = acc0 + acc1;
      float inv = 1.f / (float)(r1 - r0);
      o[0] = f2bf(acc[0] * inv * a1[c + 0] + c1[c + 0]);
      o[1] = f2bf(acc[1] * inv * a1[c + 1] + c1[c + 1]);
      o[2] = f2bf(acc[2] * inv * a1[c + 2] + c1[c + 2]);
      o[3] = f2bf(acc[3] * inv * a1[c + 3] + c1[c + 3]);
    }
  }
  *(u16x4*)(conv_in + n * 512 + c) = o;
}

// kvT[b][h][d][m] += sum_i kf[i][m]*v[i][d]; kfsum[b][h][m] += sum_i kf[i][m]
// u' = u - diag is the input; kf = exp(u' - km)/16 + 1e-6 computed inline in f32
__global__ __launch_bounds__(256) void k_kv(const float* __restrict__ u,
                                            const unsigned int* __restrict__ kmax,
                                            const unsigned short* __restrict__ vh,
                                            const unsigned int* __restrict__ offs,
                                            float* __restrict__ kvT, float* __restrict__ kfsum, int h) {
  int b = blockIdx.y;
  unsigned int off = offs[b];
  int nb = (int)(offs[b + 1] - off);
  int start = blockIdx.x * 256;
  if (start >= nb) return;
  int cnt = min(256, nb - start);
  float km = __uint_as_float(kmax[b * 8 + h]);
  __shared__ float kfs[16][256];
  __shared__ float vs[16][64];
  int tid = threadIdx.x;
  int mg = tid & 63, dg = tid >> 6;
  f32x4 acc[4][4] = {};
  f32x4 sacc = {};
  for (int g0 = 0; g0 < cnt; g0 += 16) {
    int nv = min(16, cnt - g0);
    #pragma unroll
    for (int ch = tid; ch < 16 * 64; ch += 256) {
      int r = ch >> 6, c4 = (ch & 63) * 4;
      if (r < nv) {
        long node = (long)(off + start + g0 + r);
        f32x4 uv = *(const f32x4*)(u + node * 256 + c4);
        f32x4 e;
        #pragma unroll
        for (int j = 0; j < 4; j++) e[j] = __expf(uv[j] - km) * 0.0625f + 1e-6f;
        *(f32x4*)(&kfs[r][c4]) = e;
      }
    }
    {
      int r = tid >> 4, c4 = (tid & 15) * 4;
      if (r < nv) {
        u16x4 v = *(const u16x4*)(vh + (long)(off + start + g0 + r) * 64 + c4);
        #pragma unroll
        for (int j = 0; j < 4; j++) vs[r][c4 + j] = bf2f(v[j]);
      }
    }
    __syncthreads();
    for (int r = 0; r < nv; r++) {
      f32x4 kfv = *(const f32x4*)(&kfs[r][mg * 4]);
      #pragma unroll
      for (int jq = 0; jq < 4; jq++) {
        f32x4 vv = *(const f32x4*)(&vs[r][dg * 16 + jq * 4]);
        #pragma unroll
        for (int mi = 0; mi < 4; mi++) acc[mi][jq] += kfv[mi] * vv;
      }
      if (dg == 0) sacc += kfv;
    }
    __syncthreads();
  }
  long base = ((long)b * 8 + h) * 16384;
  #pragma unroll
  for (int jq = 0; jq < 4; jq++)
    #pragma unroll
    for (int dj = 0; dj < 4; dj++) {
      int d = dg * 16 + jq * 4 + dj;
      #pragma unroll
      for (int mi = 0; mi < 4; mi++)
        atomicAdd(&kvT[base + (long)d * 256 + mg * 4 + mi], acc[mi][jq][dj]);
    }
  if (dg == 0) {
    long sb = ((long)b * 8 + h) * 256 + mg * 4;
    #pragma unroll
    for (int mi = 0; mi < 4; mi++) atomicAdd(&kfsum[sb + mi], sacc[mi]);
  }
}

__global__ void k_f32_to_bf16_4(const float* __restrict__ in, unsigned short* __restrict__ out, long n) {
  long i = ((long)blockIdx.x * 256 + threadIdx.x) * 4;
  if (i >= n) return;
  f32x4 v = *(const f32x4*)(in + i);
  u16x4 o;
  o[0] = f2bf(v[0]); o[1] = f2bf(v[1]); o[2] = f2bf(v[2]); o[3] = f2bf(v[3]);
  *(u16x4*)(out + i) = o;
}

__global__ void k_sum_x_stats(const float* __restrict__ x, float* __restrict__ y,
                              float* __restrict__ s1, float* __restrict__ s2, int N, int rpb) {
  int t = threadIdx.x;
  int r0 = blockIdx.x * rpb;
  int r1 = min(N, r0 + rpb);
  float a1 = 0, a2 = 0, b1 = 0, b2 = 0;
  for (int r = r0; r < r1; r++) {
    long ia = (long)r * 512 + t;
    long ib = ia + 256;
    float va = x[ia] + y[ia];
    float vb = x[ib] + y[ib];
    y[ia] = va; y[ib] = vb;
    a1 += va; a2 += va * va; b1 += vb; b2 += vb * vb;
  }
  atomicAdd(&s1[t], a1); atomicAdd(&s2[t], a2);
  atomicAdd(&s1[t + 256], b1); atomicAdd(&s2[t + 256], b2);
}

__global__ void k_bn_apply(float* __restrict__ y, const float* __restrict__ a,
                           const float* __restrict__ c, long total) {
  long i4 = ((long)blockIdx.x * 256 + threadIdx.x) * 4;
  if (i4 >= total) return;
  int col = (int)(i4 & 511);
  f32x4 v = *(const f32x4*)(y + i4);
  #pragma unroll
  for (int j = 0; j < 4; j++) v[j] = v[j] * a[col + j] + c[col + j];
  *(f32x4*)(y + i4) = v;
}

// ===== host =====

extern "C" void kernel_launch(void* const* d_in, const int* in_sizes, int n_in,
                              void* d_out, int out_size, void* d_ws, size_t ws_size,
                              hipStream_t stream) {
  (void)n_in; (void)out_size;
  const float* x = (const float*)d_in[0];
  const int* batch = (const int*)d_in[1];
  const int* eidx = (const int*)d_in[2];
  const float* n1g = (const float*)d_in[3];
  const float* n1b = (const float*)d_in[4];
  const float* n2g = (const float*)d_in[5];
  const float* n2b = (const float*)d_in[6];
  const float* wconv = (const float*)d_in[7];
  const float* bconv = (const float*)d_in[8];
  const float* wq = (const float*)d_in[9];
  const float* wk = (const float*)d_in[10];
  const float* wv = (const float*)d_in[11];
  const float* wo = (const float*)d_in[12];
  const float* proj = (const float*)d_in[13];

  const int N = in_sizes[1];
  const long E = in_sizes[2] / 2;
  const long Npad = CDIV(N, 128) * 128 + 128;  // +128: q-flash tail blocks may read up to N+62
  const int Mb = (int)(Npad / 128);
  const int* es = eidx;
  const int* ed = eidx + E;
  float* out = (float*)d_out;

  char* p = (char*)d_ws;
  auto alloc = [&](size_t bytes) -> char* {
    char* r = p;
    p += (bytes + 255) & ~(size_t)255;
    return r;
  };
  float*          ubuf = (float*)alloc((size_t)Npad * 256 * 4);               // u' = u - diag (k-side)
  unsigned short* kvqh = (unsigned short*)alloc((size_t)24 * Npad * 64 * 2);  // q:0-7,k:8-15,v:16-23
  unsigned short* xbf  = (unsigned short*)alloc((size_t)Npad * 512 * 2);      // -> attn_all -> conv_in
  float*          kvT_f = (float*)alloc((size_t)32 * 8 * 16384 * 4);
  unsigned short* kvT_b = (unsigned short*)alloc((size_t)32 * 8 * 16384 * 2);
  unsigned short* wts   = (unsigned short*)alloc((size_t)5 * 512 * 512 * 2);  // q|k|v|conv|o transposed
  unsigned short* proj_s = (unsigned short*)alloc((size_t)256 * 64 * 2);
  float* bn1_acc = (float*)alloc(1024 * 4);
  float* bn1_ac  = (float*)alloc(1024 * 4);
  float* bn2_acc = (float*)alloc(1024 * 4);
  float* bn2_ac  = (float*)alloc(1024 * 4);
  unsigned int* deg      = (unsigned int*)alloc((size_t)N * 4);
  unsigned int* offs     = (unsigned int*)alloc(33 * 4);
  unsigned int* kmax     = (unsigned int*)alloc(32 * 8 * 4);
  float* kfsum = (float*)alloc((size_t)32 * 8 * 256 * 4);
  unsigned int* rowstart = (unsigned int*)alloc((size_t)(N + 1) * 4);
  unsigned int* cursor   = (unsigned int*)alloc((size_t)N * 4);
  int* csr               = (int*)alloc((size_t)E * 4);
  size_t required = (size_t)(p - (char*)d_ws);
  if (required > ws_size) {
    k_fill<<<(int)CDIV((long)N * 512, 256), 256, 0, stream>>>(
        out, (long)N * 512, 1.0e6f + (float)(ws_size >> 20));
    return;
  }
  unsigned short* wqkv_t  = wts;
  unsigned short* wconv_t = wts + 3 * 512 * 512;
  unsigned short* wo_t    = wts + 4 * 512 * 512;
  unsigned short* attn_all = xbf;
  unsigned short* conv_in  = xbf;

  // ---- zero accumulators (ws is not re-poisoned between replays) ----
  hipMemsetAsync(deg, 0, (size_t)N * 4, stream);
  hipMemsetAsync(cursor, 0, (size_t)N * 4, stream);
  hipMemsetAsync(kvT_f, 0, (size_t)32 * 8 * 16384 * 4, stream);
  hipMemsetAsync(kfsum, 0, (size_t)32 * 8 * 256 * 4, stream);
  hipMemsetAsync(kmax, 0, 32 * 8 * 4, stream);
  hipMemsetAsync(bn1_acc, 0, 1024 * 4, stream);
  hipMemsetAsync(bn2_acc, 0, 1024 * 4, stream);

  // ---- prep ----
  k_convert_x<<<(int)CDIV(Npad * 512 / 4, 256), 256, 0, stream>>>(x, xbf, Npad * 512, (long)N * 512);
  k_transall<<<(int)CDIV(5L << 18, 256), 256, 0, stream>>>(wq, wk, wv, wconv, wo, wts);
  k_scale_copy_bf<<<CDIV(256 * 64, 256), 256, 0, stream>>>(proj, proj_s, 256 * 64, 0.35355339059327373f);

  int rpb = CDIV(N, 1024);
  k_bn_stats<<<1024, 256, 0, stream>>>(x, bn1_acc, bn1_acc + 512, N, rpb);
  k_bn_final<<<1, 512, 0, stream>>>(bn1_acc, bn1_acc + 512, n1g, n1b, bn1_ac, bn1_ac + 512, 1.f / N);
  k_deg<<<(int)CDIV(E, 256), 256, 0, stream>>>(ed, deg, E);
  k_offs<<<CDIV(N, 256), 256, 0, stream>>>(batch, offs, N);
  k_scan_nodes<<<1, 1024, 0, stream>>>(deg, rowstart, N);
  k_csr_fill<<<(int)CDIV(E, 256), 256, 0, stream>>>(es, ed, rowstart, cursor, csr, E);

  // ---- QKV: one GEMM, epilogue remaps cols to per-head-z layout [z][Npad][64] ----
  gemm_bt<128, 128, 2, 2, 7><<<dim3(12, Mb), 256, 0, stream>>>(
      xbf, wqkv_t, kvqh, nullptr, nullptr, nullptr,
      512, 512, 512, 0, (long)Npad * 64, (int)Npad, 0);

  // ---- keys pass: u'-GEMM (fused diag + kmax) then fused-exp kv accumulation ----
  for (int h = 0; h < 8; h++) {
    const unsigned short* kh = kvqh + (long)(8 + h) * Npad * 64;
    const unsigned short* vh = kvqh + (long)(16 + h) * Npad * 64;
    gemm_bt<64, 256, 1, 4, 6><<<dim3(1, (int)(Npad / 64)), 256, 0, stream>>>(
        kh, proj_s, ubuf, nullptr, kmax, batch, 64, 64, 64, 256, 0, N, h);
    k_kv<<<dim3(8, 32), 256, 0, stream>>>(ubuf, kmax, vh, offs, kvT_f, kfsum, h);
  }
  k_f32_to_bf16_4<<<CDIV((long)32 * 8 * 16384 / 4, 256), 256, 0, stream>>>(
      kvT_f, kvT_b, (long)32 * 8 * 16384);

  // ---- queries pass: single fused flash kernel over (blocks, graphs, heads) ----
  k_qflash<<<dim3(32, 32, 8), 256, 0, stream>>>(
      kvqh, proj_s, kvT_b, kfsum, offs, attn_all, Npad);

  // ---- output projection (full overwrite of out) ----
  gemm_bt<128, 128, 2, 2, 0><<<dim3(4, Mb), 256, 0, stream>>>(
      attn_all, wo_t, out, nullptr, nullptr, nullptr, 512, 512, 512, 512, 0, N, 0);

  // ---- GNN conv path: CSR gather (fused BN1-affine + normalize + bf16) ----
  k_gather<<<(int)Npad, 128, 0, stream>>>(csr, rowstart, x, bn1_ac, bn1_ac + 512, conv_in, N);
  gemm_bt<128, 128, 2, 2, 5><<<dim3(4, Mb), 256, 0, stream>>>(
      conv_in, wconv_t, out, bconv, nullptr, nullptr, 512, 512, 512, 512, 0, N, 0);

  // ---- residual + BN2 ----
  k_sum_x_stats<<<1024, 256, 0, stream>>>(x, out, bn2_acc, bn2_acc + 512, N, rpb);
  k_bn_final<<<1, 512, 0, stream>>>(bn2_acc, bn2_acc + 512, n2g, n2b, bn2_ac, bn2_ac + 512, 1.f / N);
  k_bn_apply<<<(int)CDIV((long)N * 512 / 4, 256), 256, 0, stream>>>(out, bn2_ac, bn2_ac + 512, (long)N * 512);
}

// Round 5
// 1301.541 us; speedup vs baseline: 4.7659x; 1.9865x over previous
//
#include <hip/hip_runtime.h>
#include <stdint.h>

#define CDIV(a,b) (((a)+(b)-1)/(b))

typedef __attribute__((ext_vector_type(4))) float f32x4;
typedef __attribute__((ext_vector_type(8))) short s16x8;
typedef __attribute__((ext_vector_type(8))) unsigned short u16x8;
typedef __attribute__((ext_vector_type(4))) unsigned short u16x4;

__device__ __forceinline__ float bf2f(unsigned short u) {
  union { unsigned int i; float f; } c; c.i = ((unsigned int)u) << 16; return c.f;
}
__device__ __forceinline__ unsigned short f2bf(float f) {
  union { float f; unsigned int i; } c; c.f = f;
  unsigned int u = c.i;
  u += 0x7fffu + ((u >> 16) & 1u);
  return (unsigned short)(u >> 16);
}

// ===== GEMM: C[M,N] = A(bf16)[M,K] * B(bf16)[N,K]^T =====
// EPI: 5 = f32 += relu(acc + aux[col])
//      7 = bf16 store remapped col -> (z = col>>6): C[z*zsC + r*64 + (col&63)]
//      8 = f32 store acc + aux[ci]  (residual add, aux indexed like C)
template<int BM, int BN, int WM, int WN, int EPI>
__global__ __launch_bounds__(256) void gemm_bt(
    const unsigned short* __restrict__ A, const unsigned short* __restrict__ B,
    void* __restrict__ Cout, const float* __restrict__ aux,
    int K, int lda, int ldb, int ldc, long zsC, int Mstore)
{
  constexpr int MT = BM / (WM * 16);
  constexpr int NT = BN / (WN * 16);
  constexpr int LDT = 40;
  __shared__ unsigned short As[BM * LDT];
  __shared__ unsigned short Bs[BN * LDT];
  const int tid = threadIdx.x, wid = tid >> 6, lane = tid & 63;
  const int wr = wid / WN, wc = wid % WN;
  long m0 = (long)blockIdx.y * BM;
  const int n0 = blockIdx.x * BN;
  f32x4 acc[MT][NT] = {};
  for (int k0 = 0; k0 < K; k0 += 32) {
    #pragma unroll
    for (int c = tid; c < BM * 4; c += 256) {
      int row = c >> 2, c8 = (c & 3) * 8;
      *(u16x8*)(&As[row * LDT + c8]) = *(const u16x8*)(A + (m0 + row) * lda + k0 + c8);
    }
    #pragma unroll
    for (int c = tid; c < BN * 4; c += 256) {
      int row = c >> 2, c8 = (c & 3) * 8;
      *(u16x8*)(&Bs[row * LDT + c8]) = *(const u16x8*)(B + (long)(n0 + row) * ldb + k0 + c8);
    }
    __syncthreads();
    s16x8 af[MT], bfv[NT];
    #pragma unroll
    for (int mt = 0; mt < MT; mt++)
      af[mt] = *(const s16x8*)(&As[(wr * MT * 16 + mt * 16 + (lane & 15)) * LDT + ((lane >> 4) * 8)]);
    #pragma unroll
    for (int nt = 0; nt < NT; nt++)
      bfv[nt] = *(const s16x8*)(&Bs[(wc * NT * 16 + nt * 16 + (lane & 15)) * LDT + ((lane >> 4) * 8)]);
    #pragma unroll
    for (int mt = 0; mt < MT; mt++)
      #pragma unroll
      for (int nt = 0; nt < NT; nt++)
        acc[mt][nt] = __builtin_amdgcn_mfma_f32_16x16x32_bf16(af[mt], bfv[nt], acc[mt][nt], 0, 0, 0);
    __syncthreads();
  }
  #pragma unroll
  for (int mt = 0; mt < MT; mt++) {
    const int rl0 = wr * (MT * 16) + mt * 16 + ((lane >> 4) << 2);
    #pragma unroll
    for (int nt = 0; nt < NT; nt++) {
      const int col = n0 + wc * (NT * 16) + nt * 16 + (lane & 15);
      #pragma unroll
      for (int i = 0; i < 4; i++) {
        long r = m0 + rl0 + i;
        if (r < Mstore) {
          float v = acc[mt][nt][i];
          long ci = r * ldc + col;
          if constexpr (EPI == 5) {
            float o = v + aux[col];
            o = o > 0.f ? o : 0.f;
            ((float*)Cout)[ci] += o;
          } else if constexpr (EPI == 7) {
            ((unsigned short*)Cout)[(long)(col >> 6) * zsC + r * 64 + (col & 63)] = f2bf(v);
          } else if constexpr (EPI == 8) {
            ((float*)Cout)[ci] = v + aux[ci];
          }
        }
      }
    }
  }
}

// ===== k-side pass 1: per-graph-per-head max of u (no stores) =====
__global__ __launch_bounds__(256) void k_kmax(
    const unsigned short* __restrict__ kvqh, const unsigned short* __restrict__ projb,
    const unsigned int* __restrict__ offs, unsigned int* __restrict__ kmax, long Npad) {
  __shared__ float wmax[4];
  const int tid = threadIdx.x, wid = tid >> 6, lane = tid & 63;
  const int b = blockIdx.y, h = blockIdx.z;
  const unsigned int off = offs[b];
  const int nb = (int)(offs[b + 1] - off);
  const int m0 = blockIdx.x * 64;
  if (m0 >= nb) return;
  const unsigned short* A = kvqh + ((long)(8 + h) * Npad + off + m0) * 64;
  f32x4 acc[4][4] = {};
  #pragma unroll
  for (int k0 = 0; k0 < 64; k0 += 32) {
    s16x8 af[4], bfv[4];
    #pragma unroll
    for (int mt = 0; mt < 4; mt++)
      af[mt] = *(const s16x8*)(A + (long)(mt * 16 + (lane & 15)) * 64 + k0 + ((lane >> 4) * 8));
    #pragma unroll
    for (int nt = 0; nt < 4; nt++)
      bfv[nt] = *(const s16x8*)(projb + (long)(wid * 64 + nt * 16 + (lane & 15)) * 64 + k0 + ((lane >> 4) * 8));
    #pragma unroll
    for (int mt = 0; mt < 4; mt++)
      #pragma unroll
      for (int nt = 0; nt < 4; nt++)
        acc[mt][nt] = __builtin_amdgcn_mfma_f32_16x16x32_bf16(af[mt], bfv[nt], acc[mt][nt], 0, 0, 0);
  }
  float bm = -3.0e38f;
  #pragma unroll
  for (int mt = 0; mt < 4; mt++)
    #pragma unroll
    for (int i = 0; i < 4; i++) {
      int row = mt * 16 + ((lane >> 4) << 2) + i;
      if (m0 + row < nb) {
        #pragma unroll
        for (int nt = 0; nt < 4; nt++) bm = fmaxf(bm, acc[mt][nt][i]);
      }
    }
  #pragma unroll
  for (int s = 1; s < 64; s <<= 1) bm = fmaxf(bm, __shfl_xor(bm, s));
  if (lane == 0) wmax[wid] = bm;
  __syncthreads();
  if (tid == 0) {
    float m = fmaxf(fmaxf(wmax[0], wmax[1]), fmaxf(wmax[2], wmax[3]));
    atomicMax(&kmax[b * 8 + h], __float_as_uint(fmaxf(m, 0.f)));
  }
}

// ===== k-side pass 2: fused u-recompute + exp + kv/kfsum accumulation (one block per (b,h)) =====
__global__ __launch_bounds__(256) void k_kvf(
    const unsigned short* __restrict__ kvqh, const unsigned short* __restrict__ projb,
    const unsigned int* __restrict__ offs, const unsigned int* __restrict__ kmax,
    unsigned short* __restrict__ kvTb, float* __restrict__ kfsum, long Npad) {
  constexpr int TLD = 72;
  __shared__ unsigned short kfsT[256 * TLD];  // kf^T [m][r]
  __shared__ unsigned short vsT[64 * TLD];    // v^T  [d][r]
  __shared__ float kfacc[256];
  __shared__ float sdiag[64];
  const int tid = threadIdx.x, wid = tid >> 6, lane = tid & 63;
  const int b = blockIdx.x, h = blockIdx.y;
  const unsigned int off = offs[b];
  const int nb = (int)(offs[b + 1] - off);
  const float km = __uint_as_float(kmax[b * 8 + h]);
  const unsigned short* Kp = kvqh + ((long)(8 + h) * Npad + off) * 64;
  const unsigned short* Vp = kvqh + ((long)(16 + h) * Npad + off) * 64;
  kfacc[tid] = 0.f;
  f32x4 akv[16] = {};
  for (int m0 = 0; m0 < nb; m0 += 64) {
    // --- u tile via direct-global MFMA fragments ---
    f32x4 acc[4][4] = {};
    float dsum[4] = {0.f, 0.f, 0.f, 0.f};
    #pragma unroll
    for (int k0 = 0; k0 < 64; k0 += 32) {
      s16x8 af[4], bfv[4];
      #pragma unroll
      for (int mt = 0; mt < 4; mt++)
        af[mt] = *(const s16x8*)(Kp + ((long)m0 + mt * 16 + (lane & 15)) * 64 + k0 + ((lane >> 4) * 8));
      #pragma unroll
      for (int nt = 0; nt < 4; nt++)
        bfv[nt] = *(const s16x8*)(projb + (long)(wid * 64 + nt * 16 + (lane & 15)) * 64 + k0 + ((lane >> 4) * 8));
      if (wid == 0) {
        #pragma unroll
        for (int mt = 0; mt < 4; mt++)
          #pragma unroll
          for (int j = 0; j < 8; j++) {
            float a = bf2f((unsigned short)af[mt][j]);
            dsum[mt] += a * a;
          }
      }
      #pragma unroll
      for (int mt = 0; mt < 4; mt++)
        #pragma unroll
        for (int nt = 0; nt < 4; nt++)
          acc[mt][nt] = __builtin_amdgcn_mfma_f32_16x16x32_bf16(af[mt], bfv[nt], acc[mt][nt], 0, 0, 0);
    }
    __syncthreads();  // previous chunk's MFMA (kfsT/vsT readers) done
    if (wid == 0) {
      #pragma unroll
      for (int mt = 0; mt < 4; mt++) {
        float s = dsum[mt];
        s += __shfl_xor(s, 16); s += __shfl_xor(s, 32);
        if (lane < 16) sdiag[mt * 16 + lane] = 0.0625f * s;
      }
    }
    // --- stage v^T ---
    #pragma unroll
    for (int c = tid; c < 512; c += 256) {
      int row = c >> 3, c8 = (c & 7) * 8;
      u16x8 v = *(const u16x8*)(Vp + ((long)m0 + row) * 64 + c8);
      #pragma unroll
      for (int j = 0; j < 8; j++) vsT[(c8 + j) * TLD + row] = v[j];
    }
    __syncthreads();  // sdiag + vsT visible
    // --- exp -> kf^T (bf16, packed u32 writes) + kfsum accumulation ---
    #pragma unroll
    for (int nt = 0; nt < 4; nt++) {
      int m = wid * 64 + nt * 16 + (lane & 15);
      float esum = 0.f;
      #pragma unroll
      for (int mt = 0; mt < 4; mt++) {
        int r0 = mt * 16 + ((lane >> 4) << 2);
        float e0, e1, e2, e3;
        {
          int g0 = m0 + r0;
          e0 = (g0 + 0 < nb) ? (__expf(acc[mt][nt][0] - sdiag[r0 + 0] - km) * 0.0625f + 1e-6f) : 0.f;
          e1 = (g0 + 1 < nb) ? (__expf(acc[mt][nt][1] - sdiag[r0 + 1] - km) * 0.0625f + 1e-6f) : 0.f;
          e2 = (g0 + 2 < nb) ? (__expf(acc[mt][nt][2] - sdiag[r0 + 2] - km) * 0.0625f + 1e-6f) : 0.f;
          e3 = (g0 + 3 < nb) ? (__expf(acc[mt][nt][3] - sdiag[r0 + 3] - km) * 0.0625f + 1e-6f) : 0.f;
        }
        esum += e0 + e1 + e2 + e3;
        unsigned int p0 = (unsigned int)f2bf(e0) | ((unsigned int)f2bf(e1) << 16);
        unsigned int p1 = (unsigned int)f2bf(e2) | ((unsigned int)f2bf(e3) << 16);
        *(unsigned int*)(&kfsT[m * TLD + r0]) = p0;
        *(unsigned int*)(&kfsT[m * TLD + r0 + 2]) = p1;
      }
      atomicAdd(&kfacc[m], esum);
    }
    __syncthreads();  // kfsT visible
    // --- kv accumulation: D[d][m] += v^T . kf, wave wid owns d-tile wid ---
    #pragma unroll
    for (int ks = 0; ks < 2; ks++) {
      s16x8 aA = *(const s16x8*)(&vsT[(wid * 16 + (lane & 15)) * TLD + ks * 32 + ((lane >> 4) * 8)]);
      #pragma unroll
      for (int mt2 = 0; mt2 < 16; mt2++) {
        s16x8 bB = *(const s16x8*)(&kfsT[(mt2 * 16 + (lane & 15)) * TLD + ks * 32 + ((lane >> 4) * 8)]);
        akv[mt2] = __builtin_amdgcn_mfma_f32_16x16x32_bf16(aA, bB, akv[mt2], 0, 0, 0);
      }
    }
  }
  long base = ((long)b * 8 + h) * 16384;
  #pragma unroll
  for (int mt2 = 0; mt2 < 16; mt2++)
    #pragma unroll
    for (int i = 0; i < 4; i++) {
      int d = wid * 16 + ((lane >> 4) << 2) + i;
      kvTb[base + (long)d * 256 + mt2 * 16 + (lane & 15)] = f2bf(akv[mt2][i]);
    }
  kfsum[((long)b * 8 + h) * 256 + tid] = kfacc[tid];
}

// ===== fused query-side flash kernel (no A/B LDS staging) =====
__global__ __launch_bounds__(256) void k_qflash(
    const unsigned short* __restrict__ qh_all, const unsigned short* __restrict__ projb,
    const unsigned short* __restrict__ kvTb, const float* __restrict__ kfsum,
    const unsigned int* __restrict__ offs, unsigned short* __restrict__ attn, long Npad) {
  constexpr int QLDT = 264;
  __shared__ unsigned short qfs[64 * QLDT];
  __shared__ float skf[256];
  __shared__ float sdiag[64];
  __shared__ float smax[4][64];
  __shared__ float szp[4][64];
  const int tid = threadIdx.x, wid = tid >> 6, lane = tid & 63;
  const int b = blockIdx.y, h = blockIdx.z;
  const unsigned int off = offs[b];
  const int nb = (int)(offs[b + 1] - off);
  const int m0 = blockIdx.x * 64;
  if (m0 >= nb) return;
  const unsigned short* A = qh_all + ((long)h * Npad + off + m0) * 64;
  skf[tid] = kfsum[((long)b * 8 + h) * 256 + tid];
  f32x4 acc[4][4] = {};
  float dsum[4] = {0.f, 0.f, 0.f, 0.f};
  #pragma unroll
  for (int k0 = 0; k0 < 64; k0 += 32) {
    s16x8 af[4], bfv[4];
    #pragma unroll
    for (int mt = 0; mt < 4; mt++)
      af[mt] = *(const s16x8*)(A + (long)(mt * 16 + (lane & 15)) * 64 + k0 + ((lane >> 4) * 8));
    #pragma unroll
    for (int nt = 0; nt < 4; nt++)
      bfv[nt] = *(const s16x8*)(projb + (long)(wid * 64 + nt * 16 + (lane & 15)) * 64 + k0 + ((lane >> 4) * 8));
    if (wid == 0) {
      #pragma unroll
      for (int mt = 0; mt < 4; mt++)
        #pragma unroll
        for (int j = 0; j < 8; j++) {
          float a = bf2f((unsigned short)af[mt][j]);
          dsum[mt] += a * a;
        }
    }
    #pragma unroll
    for (int mt = 0; mt < 4; mt++)
      #pragma unroll
      for (int nt = 0; nt < 4; nt++)
        acc[mt][nt] = __builtin_amdgcn_mfma_f32_16x16x32_bf16(af[mt], bfv[nt], acc[mt][nt], 0, 0, 0);
  }
  if (wid == 0) {
    #pragma unroll
    for (int mt = 0; mt < 4; mt++) {
      float s = dsum[mt];
      s += __shfl_xor(s, 16); s += __shfl_xor(s, 32);
      if (lane < 16) sdiag[mt * 16 + lane] = 0.0625f * s;
    }
  }
  #pragma unroll
  for (int mt = 0; mt < 4; mt++)
    #pragma unroll
    for (int i = 0; i < 4; i++) {
      float rm = fmaxf(fmaxf(acc[mt][0][i], acc[mt][1][i]), fmaxf(acc[mt][2][i], acc[mt][3][i]));
      rm = fmaxf(rm, __shfl_xor(rm, 1)); rm = fmaxf(rm, __shfl_xor(rm, 2));
      rm = fmaxf(rm, __shfl_xor(rm, 4)); rm = fmaxf(rm, __shfl_xor(rm, 8));
      if ((lane & 15) == 0) smax[wid][mt * 16 + ((lane >> 4) << 2) + i] = rm;
    }
  __syncthreads();
  #pragma unroll
  for (int mt = 0; mt < 4; mt++)
    #pragma unroll
    for (int i = 0; i < 4; i++) {
      int row = mt * 16 + ((lane >> 4) << 2) + i;
      float rm = fmaxf(fmaxf(smax[0][row], smax[1][row]), fmaxf(smax[2][row], smax[3][row]));
      float dg = sdiag[row];
      float zp = 0.f;
      #pragma unroll
      for (int nt = 0; nt < 4; nt++) {
        int col = wid * 64 + nt * 16 + (lane & 15);
        float e = __expf(acc[mt][nt][i] - dg - rm) * 0.0625f + 1e-6f;
        qfs[row * QLDT + col] = f2bf(e);
        zp += e * skf[col];
      }
      zp += __shfl_xor(zp, 1); zp += __shfl_xor(zp, 2);
      zp += __shfl_xor(zp, 4); zp += __shfl_xor(zp, 8);
      if ((lane & 15) == 0) szp[wid][row] = zp;
    }
  __syncthreads();
  const unsigned short* kvb = kvTb + ((long)b * 8 + h) * 16384;
  f32x4 acc2[4] = {};
  #pragma unroll
  for (int ks = 0; ks < 8; ks++) {
    s16x8 aq = *(const s16x8*)(&qfs[(wid * 16 + (lane & 15)) * QLDT + ks * 32 + ((lane >> 4) * 8)]);
    #pragma unroll
    for (int ntd = 0; ntd < 4; ntd++) {
      s16x8 bk = *(const s16x8*)(kvb + (long)(ntd * 16 + (lane & 15)) * 256 + ks * 32 + ((lane >> 4) * 8));
      acc2[ntd] = __builtin_amdgcn_mfma_f32_16x16x32_bf16(aq, bk, acc2[ntd], 0, 0, 0);
    }
  }
  #pragma unroll
  for (int ntd = 0; ntd < 4; ntd++)
    #pragma unroll
    for (int i = 0; i < 4; i++) {
      int row = wid * 16 + ((lane >> 4) << 2) + i;
      if (m0 + row < nb) {
        float zr = 1.f / (szp[0][row] + szp[1][row] + szp[2][row] + szp[3][row] + 1e-6f);
        attn[(long)(off + m0 + row) * 512 + h * 64 + ntd * 16 + (lane & 15)] = f2bf(acc2[ntd][i] * zr);
      }
    }
}

// ===== small kernels =====

__global__ void k_fill(float* __restrict__ out, long n, float v) {
  long i = (long)blockIdx.x * 256 + threadIdx.x;
  if (i < n) out[i] = v;
}

__global__ void k_convert_x(const float* __restrict__ x, unsigned short* __restrict__ xb,
                            long ntotal, long nreal) {
  long i = ((long)blockIdx.x * 256 + threadIdx.x) * 4;
  if (i >= ntotal) return;
  u16x4 o;
  if (i < nreal) {
    f32x4 v = *(const f32x4*)(x + i);
    o[0] = f2bf(v[0]); o[1] = f2bf(v[1]); o[2] = f2bf(v[2]); o[3] = f2bf(v[3]);
  } else { o[0] = 0; o[1] = 0; o[2] = 0; o[3] = 0; }
  *(u16x4*)(xb + i) = o;
}

__global__ void k_transall(const float* __restrict__ w0, const float* __restrict__ w1,
                           const float* __restrict__ w2, const float* __restrict__ w3,
                           const float* __restrict__ w4, unsigned short* __restrict__ out) {
  long idx = (long)blockIdx.x * 256 + threadIdx.x;
  if (idx >= (5L << 18)) return;
  int which = (int)(idx >> 18);
  int r = (int)(idx & 262143);
  int n = r >> 9, k = r & 511;
  const float* w = which == 0 ? w0 : which == 1 ? w1 : which == 2 ? w2 : which == 3 ? w3 : w4;
  out[idx] = f2bf(w[k * 512 + n]);
}

__global__ void k_scale_copy_bf(const float* __restrict__ in, unsigned short* __restrict__ out,
                                int n, float scl) {
  int i = blockIdx.x * 256 + threadIdx.x;
  if (i < n) out[i] = f2bf(in[i] * scl);
}

__global__ void k_bn_stats(const float* __restrict__ x, float* __restrict__ s1,
                           float* __restrict__ s2, int N, int rpb) {
  int t = threadIdx.x;
  int r0 = blockIdx.x * rpb;
  int r1 = min(N, r0 + rpb);
  float a1 = 0, a2 = 0, b1 = 0, b2 = 0;
  for (int r = r0; r < r1; r++) {
    float va = x[(long)r * 512 + t];
    float vb = x[(long)r * 512 + t + 256];
    a1 += va; a2 += va * va; b1 += vb; b2 += vb * vb;
  }
  atomicAdd(&s1[t], a1); atomicAdd(&s2[t], a2);
  atomicAdd(&s1[t + 256], b1); atomicAdd(&s2[t + 256], b2);
}

__global__ void k_bn_final(const float* __restrict__ s1, const float* __restrict__ s2,
                           const float* __restrict__ g, const float* __restrict__ b,
                           float* __restrict__ a, float* __restrict__ c, float invN) {
  int t = threadIdx.x;
  float mu = s1[t] * invN;
  float var = s2[t] * invN - mu * mu;
  float inv = rsqrtf(var + 1e-5f);
  float av = g[t] * inv;
  a[t] = av;
  c[t] = b[t] - mu * av;
}

__global__ void k_deg(const int* __restrict__ ed, unsigned int* __restrict__ deg, long E) {
  long i = (long)blockIdx.x * 256 + threadIdx.x;
  if (i < E) atomicAdd(&deg[ed[i]], 1u);
}

__global__ void k_offs(const int* __restrict__ batch, unsigned int* __restrict__ offs, int N) {
  int i = blockIdx.x * 256 + threadIdx.x;
  if (i >= N) return;
  int b = batch[i];
  if (i == 0) { for (int bb = 0; bb <= b; bb++) offs[bb] = 0; }
  else {
    int pb = batch[i - 1];
    if (pb != b) for (int bb = pb + 1; bb <= b; bb++) offs[bb] = i;
  }
  if (i == N - 1) { for (int bb = b + 1; bb <= 32; bb++) offs[bb] = N; }
}

__global__ __launch_bounds__(1024) void k_scan_nodes(const unsigned int* __restrict__ deg,
                                                     unsigned int* __restrict__ rowstart, int N) {
  __shared__ unsigned int wsum[16];
  __shared__ unsigned int carry_s;
  int t = threadIdx.x, lane = t & 63, wid = t >> 6;
  if (t == 0) carry_s = 0;
  __syncthreads();
  for (int base = 0; base < N; base += 1024) {
    int i = base + t;
    unsigned int v = (i < N) ? deg[i] : 0;
    unsigned int sc = v;
    #pragma unroll
    for (int s = 1; s < 64; s <<= 1) {
      unsigned int u = __shfl_up(sc, s);
      if (lane >= s) sc += u;
    }
    if (lane == 63) wsum[wid] = sc;
    __syncthreads();
    unsigned int woff = 0, tot = 0;
    #pragma unroll
    for (int w = 0; w < 16; w++) { unsigned int s = wsum[w]; if (w < wid) woff += s; tot += s; }
    unsigned int carry = carry_s;
    if (i < N) rowstart[i] = carry + woff + sc - v;
    __syncthreads();
    if (t == 0) carry_s = carry + tot;
    __syncthreads();
  }
  if (threadIdx.x == 0) rowstart[N] = carry_s;
}

__global__ void k_csr_fill(const int* __restrict__ es, const int* __restrict__ ed,
                           const unsigned int* __restrict__ rowstart,
                           unsigned int* __restrict__ cursor, int* __restrict__ csr, long E) {
  long e = (long)blockIdx.x * 256 + threadIdx.x;
  if (e >= E) return;
  int d = ed[e];
  unsigned int slot = atomicAdd(&cursor[d], 1u);
  csr[rowstart[d] + slot] = es[e];
}

__global__ __launch_bounds__(128) void k_gather(const int* __restrict__ csr,
                                                const unsigned int* __restrict__ rowstart,
                                                const float* __restrict__ x,
                                                const float* __restrict__ a1, const float* __restrict__ c1,
                                                unsigned short* __restrict__ conv_in, int N) {
  long n = blockIdx.x;
  int c = threadIdx.x * 4;
  u16x4 o; o[0] = 0; o[1] = 0; o[2] = 0; o[3] = 0;
  if (n < N) {
    unsigned int r0 = rowstart[n], r1 = rowstart[n + 1];
    if (r1 > r0) {
      f32x4 acc0 = {}, acc1 = {};
      unsigned int j = r0;
      for (; j + 2 <= r1; j += 2) {
        int s0 = csr[j], s1 = csr[j + 1];
        acc0 += *(const f32x4*)(x + (long)s0 * 512 + c);
        acc1 += *(const f32x4*)(x + (long)s1 * 512 + c);
      }
      if (j < r1) { int s0 = csr[j]; acc0 += *(const f32x4*)(x + (long)s0 * 512 + c); }
      f32x4 acc = acc0 + acc1;
      float inv = 1.f / (float)(r1 - r0);
      o[0] = f2bf(acc[0] * inv * a1[c + 0] + c1[c + 0]);
      o[1] = f2bf(acc[1] * inv * a1[c + 1] + c1[c + 1]);
      o[2] = f2bf(acc[2] * inv * a1[c + 2] + c1[c + 2]);
      o[3] = f2bf(acc[3] * inv * a1[c + 3] + c1[c + 3]);
    }
  }
  *(u16x4*)(conv_in + n * 512 + c) = o;
}

// BN2 stats only (out already holds attn@Wo + x + relu-conv)
__global__ void k_stats(const float* __restrict__ y, float* __restrict__ s1,
                        float* __restrict__ s2, int N, int rpb) {
  int t = threadIdx.x;
  int r0 = blockIdx.x * rpb;
  int r1 = min(N, r0 + rpb);
  float a1 = 0, a2 = 0, b1 = 0, b2 = 0;
  for (int r = r0; r < r1; r++) {
    float va = y[(long)r * 512 + t];
    float vb = y[(long)r * 512 + t + 256];
    a1 += va; a2 += va * va; b1 += vb; b2 += vb * vb;
  }
  atomicAdd(&s1[t], a1); atomicAdd(&s2[t], a2);
  atomicAdd(&s1[t + 256], b1); atomicAdd(&s2[t + 256], b2);
}

__global__ void k_bn_apply(float* __restrict__ y, const float* __restrict__ a,
                           const float* __restrict__ c, long total) {
  long i4 = ((long)blockIdx.x * 256 + threadIdx.x) * 4;
  if (i4 >= total) return;
  int col = (int)(i4 & 511);
  f32x4 v = *(const f32x4*)(y + i4);
  #pragma unroll
  for (int j = 0; j < 4; j++) v[j] = v[j] * a[col + j] + c[col + j];
  *(f32x4*)(y + i4) = v;
}

// ===== host =====

extern "C" void kernel_launch(void* const* d_in, const int* in_sizes, int n_in,
                              void* d_out, int out_size, void* d_ws, size_t ws_size,
                              hipStream_t stream) {
  (void)n_in; (void)out_size;
  const float* x = (const float*)d_in[0];
  const int* batch = (const int*)d_in[1];
  const int* eidx = (const int*)d_in[2];
  const float* n1g = (const float*)d_in[3];
  const float* n1b = (const float*)d_in[4];
  const float* n2g = (const float*)d_in[5];
  const float* n2b = (const float*)d_in[6];
  const float* wconv = (const float*)d_in[7];
  const float* bconv = (const float*)d_in[8];
  const float* wq = (const float*)d_in[9];
  const float* wk = (const float*)d_in[10];
  const float* wv = (const float*)d_in[11];
  const float* wo = (const float*)d_in[12];
  const float* proj = (const float*)d_in[13];

  const int N = in_sizes[1];
  const long E = in_sizes[2] / 2;
  const long Npad = CDIV(N, 128) * 128 + 128;  // +128: tail chunks may read up to N+62
  const int Mb = (int)(Npad / 128);
  const int* es = eidx;
  const int* ed = eidx + E;
  float* out = (float*)d_out;

  char* p = (char*)d_ws;
  auto alloc = [&](size_t bytes) -> char* {
    char* r = p;
    p += (bytes + 255) & ~(size_t)255;
    return r;
  };
  unsigned short* kvqh = (unsigned short*)alloc((size_t)24 * Npad * 64 * 2);  // q:0-7,k:8-15,v:16-23
  unsigned short* xbf  = (unsigned short*)alloc((size_t)Npad * 512 * 2);      // -> attn_all -> conv_in
  unsigned short* kvT_b = (unsigned short*)alloc((size_t)32 * 8 * 16384 * 2);
  unsigned short* wts   = (unsigned short*)alloc((size_t)5 * 512 * 512 * 2);  // q|k|v|conv|o transposed
  unsigned short* proj_s = (unsigned short*)alloc((size_t)256 * 64 * 2);
  float* bn1_acc = (float*)alloc(1024 * 4);
  float* bn1_ac  = (float*)alloc(1024 * 4);
  float* bn2_acc = (float*)alloc(1024 * 4);
  float* bn2_ac  = (float*)alloc(1024 * 4);
  unsigned int* deg      = (unsigned int*)alloc((size_t)N * 4);
  unsigned int* offs     = (unsigned int*)alloc(33 * 4);
  unsigned int* kmax     = (unsigned int*)alloc(32 * 8 * 4);
  float* kfsum = (float*)alloc((size_t)32 * 8 * 256 * 4);
  unsigned int* rowstart = (unsigned int*)alloc((size_t)(N + 1) * 4);
  unsigned int* cursor   = (unsigned int*)alloc((size_t)N * 4);
  int* csr               = (int*)alloc((size_t)E * 4);
  size_t required = (size_t)(p - (char*)d_ws);
  if (required > ws_size) {
    k_fill<<<(int)CDIV((long)N * 512, 256), 256, 0, stream>>>(
        out, (long)N * 512, 1.0e6f + (float)(ws_size >> 20));
    return;
  }
  unsigned short* wqkv_t  = wts;
  unsigned short* wconv_t = wts + 3 * 512 * 512;
  unsigned short* wo_t    = wts + 4 * 512 * 512;
  unsigned short* attn_all = xbf;
  unsigned short* conv_in  = xbf;

  // ---- zero accumulators (ws is not re-poisoned between replays) ----
  hipMemsetAsync(deg, 0, (size_t)N * 4, stream);
  hipMemsetAsync(cursor, 0, (size_t)N * 4, stream);
  hipMemsetAsync(kmax, 0, 32 * 8 * 4, stream);
  hipMemsetAsync(bn1_acc, 0, 1024 * 4, stream);
  hipMemsetAsync(bn2_acc, 0, 1024 * 4, stream);

  // ---- prep ----
  k_convert_x<<<(int)CDIV(Npad * 512 / 4, 256), 256, 0, stream>>>(x, xbf, Npad * 512, (long)N * 512);
  k_transall<<<(int)CDIV(5L << 18, 256), 256, 0, stream>>>(wq, wk, wv, wconv, wo, wts);
  k_scale_copy_bf<<<CDIV(256 * 64, 256), 256, 0, stream>>>(proj, proj_s, 256 * 64, 0.35355339059327373f);

  int rpb = CDIV(N, 1024);
  k_bn_stats<<<1024, 256, 0, stream>>>(x, bn1_acc, bn1_acc + 512, N, rpb);
  k_bn_final<<<1, 512, 0, stream>>>(bn1_acc, bn1_acc + 512, n1g, n1b, bn1_ac, bn1_ac + 512, 1.f / N);
  k_deg<<<(int)CDIV(E, 256), 256, 0, stream>>>(ed, deg, E);
  k_offs<<<CDIV(N, 256), 256, 0, stream>>>(batch, offs, N);
  k_scan_nodes<<<1, 1024, 0, stream>>>(deg, rowstart, N);
  k_csr_fill<<<(int)CDIV(E, 256), 256, 0, stream>>>(es, ed, rowstart, cursor, csr, E);

  // ---- QKV: one GEMM, epilogue remaps cols to per-head-z layout [z][Npad][64] ----
  gemm_bt<128, 128, 2, 2, 7><<<dim3(12, Mb), 256, 0, stream>>>(
      xbf, wqkv_t, kvqh, nullptr, 512, 512, 512, 0, (long)Npad * 64, (int)Npad);

  // ---- keys: max pass, then fused u-recompute + exp + kv (register-resident, no atomics) ----
  k_kmax<<<dim3(32, 32, 8), 256, 0, stream>>>(kvqh, proj_s, offs, kmax, Npad);
  k_kvf<<<dim3(32, 8), 256, 0, stream>>>(kvqh, proj_s, offs, kmax, kvT_b, kfsum, Npad);

  // ---- queries: fused flash kernel ----
  k_qflash<<<dim3(32, 32, 8), 256, 0, stream>>>(
      kvqh, proj_s, kvT_b, kfsum, offs, attn_all, Npad);

  // ---- output projection + residual x (EPI8 full overwrite of out) ----
  gemm_bt<128, 128, 2, 2, 8><<<dim3(4, Mb), 256, 0, stream>>>(
      attn_all, wo_t, out, x, 512, 512, 512, 512, 0, N);

  // ---- GNN conv path: CSR gather (fused BN1-affine + normalize + bf16) ----
  k_gather<<<(int)Npad, 128, 0, stream>>>(csr, rowstart, x, bn1_ac, bn1_ac + 512, conv_in, N);
  gemm_bt<128, 128, 2, 2, 5><<<dim3(4, Mb), 256, 0, stream>>>(
      conv_in, wconv_t, out, bconv, 512, 512, 512, 512, 0, N);

  // ---- BN2 ----
  k_stats<<<1024, 256, 0, stream>>>(out, bn2_acc, bn2_acc + 512, N, rpb);
  k_bn_final<<<1, 512, 0, stream>>>(bn2_acc, bn2_acc + 512, n2g, n2b, bn2_ac, bn2_ac + 512, 1.f / N);
  k_bn_apply<<<(int)CDIV((long)N * 512 / 4, 256), 256, 0, stream>>>(out, bn2_ac, bn2_ac + 512, (long)N * 512);
}